// Round 1
// baseline (14385.040 us; speedup 1.0000x reference)
//
#include <hip/hip_runtime.h>
#include <cstdint>
#include <cstddef>

#define NN 6890
#define NA 8
#define KC 15
#define ND 544
#define MR (NA * NN)                 // 55120
#define DEG 16
#define BN_EPS 1e-5f
#define NG4 ((NN + 3) / 4)           // 1723 groups of 4 nodes
#define NWAVES (NA * NG4)            // 13784
#define NBLK (NWAVES / 4)            // 3446 blocks of 4 waves

static_assert(NWAVES % 4 == 0, "wave count must fill blocks exactly");

// ---------------- fused tile(T0 build) + projection (k=0) ----------------
template<int CC, bool FIRST>
__global__ __launch_bounds__(256)
void tile_proj_kernel(const float* __restrict__ X, int C_in, int c0,
                      float* __restrict__ Tout, const float* __restrict__ Wk,
                      float* __restrict__ out_part)
{
    __shared__ float tl[4][4][CC];
    const int w    = threadIdx.x >> 6;
    const int lane = threadIdx.x & 63;
    const int wid  = blockIdx.x * 4 + w;
    const int a    = wid / NG4;
    const int n0   = (wid - a * NG4) * 4;
    const int nr   = (NN - n0) < 4 ? (NN - n0) : 4;

    if (lane < CC) {
        for (int i = 0; i < nr; ++i) {
            const float t = X[(size_t)(n0 + i) * C_in + c0 + lane];
            Tout[((size_t)a * NN + n0 + i) * CC + lane] = t;
            tl[w][i][lane] = t;
        }
    }
    __syncthreads();

    float o[4] = {0.f, 0.f, 0.f, 0.f};
    const float* wp = Wk + (size_t)a * C_in * 64 + lane;
    #pragma unroll 16
    for (int cc = 0; cc < CC; ++cc) {
        const float wv = wp[(size_t)cc * 64];
        #pragma unroll
        for (int i = 0; i < 4; ++i) o[i] += tl[w][i][cc] * wv;
    }
    for (int i = 0; i < nr; ++i) {
        const size_t idx = ((size_t)a * NN + n0 + i) * 64 + lane;
        if (FIRST) out_part[idx] = o[i];
        else       out_part[idx] += o[i];
    }
}

// ---------------- fused SpMM (+Chebyshev) + projection ----------------
// CHEB: Tio <- 2*L*Tin - Tio (in place), else Tio <- L*Tin
template<int CC, bool CHEB>
__global__ __launch_bounds__(256)
void spmm_proj_kernel(const float* __restrict__ Tin, float* __restrict__ Tio,
                      const int* __restrict__ cols, const float* __restrict__ vals,
                      const float* __restrict__ Wk, float* __restrict__ out_part,
                      int C_in)
{
    __shared__ float tl[4][4][CC];
    const int w    = threadIdx.x >> 6;
    const int lane = threadIdx.x & 63;
    const int wid  = blockIdx.x * 4 + w;
    const int a    = wid / NG4;
    const int n0   = (wid - a * NG4) * 4;
    const int nr   = (NN - n0) < 4 ? (NN - n0) : 4;

    if (lane < CC) {
        for (int i = 0; i < nr; ++i) {
            const int r  = a * NN + n0 + i;
            const int nz = r * DEG;
            float s = 0.f;
            #pragma unroll
            for (int d = 0; d < DEG; ++d)
                s += vals[nz + d] * Tin[(size_t)cols[nz + d] * CC + lane];
            float t = CHEB ? (2.f * s - Tio[(size_t)r * CC + lane]) : s;
            Tio[(size_t)r * CC + lane] = t;
            tl[w][i][lane] = t;
        }
    }
    __syncthreads();

    float o[4] = {0.f, 0.f, 0.f, 0.f};
    const float* wp = Wk + (size_t)a * C_in * 64 + lane;
    #pragma unroll 16
    for (int cc = 0; cc < CC; ++cc) {
        const float wv = wp[(size_t)cc * 64];
        #pragma unroll
        for (int i = 0; i < 4; ++i) o[i] += tl[w][i][cc] * wv;
    }
    for (int i = 0; i < nr; ++i)
        out_part[((size_t)a * NN + n0 + i) * 64 + lane] += o[i];
}

// ---------------- BN helpers ----------------
__global__ void bn_reduce_kernel(const float* __restrict__ part, float* __restrict__ acc)
{
    const int e = blockIdx.x * blockDim.x + threadIdx.x;
    if (e >= NN * 64) return;
    float s = 0.f;
    #pragma unroll
    for (int a = 0; a < NA; ++a) s += part[(size_t)a * NN * 64 + e];
    acc[e] = s;
}

__global__ __launch_bounds__(256)
void bn_stats_kernel(const float* __restrict__ acc, const float* __restrict__ gamma,
                     const float* __restrict__ beta, float* __restrict__ bnp)
{
    const int h = blockIdx.x;   // 64 blocks
    float s = 0.f, sq = 0.f;
    for (int n = threadIdx.x; n < NN; n += 256) {
        const float v = acc[(size_t)n * 64 + h];
        s += v; sq += v * v;
    }
    __shared__ float ls[256], lq[256];
    ls[threadIdx.x] = s; lq[threadIdx.x] = sq;
    __syncthreads();
    for (int st = 128; st > 0; st >>= 1) {
        if (threadIdx.x < st) { ls[threadIdx.x] += ls[threadIdx.x + st]; lq[threadIdx.x] += lq[threadIdx.x + st]; }
        __syncthreads();
    }
    if (threadIdx.x == 0) {
        const float mean = ls[0] / (float)NN;
        const float var  = lq[0] / (float)NN - mean * mean;
        const float sc   = gamma[h] / sqrtf(var + BN_EPS);
        bnp[h]      = sc;
        bnp[64 + h] = beta[h] - mean * sc;
    }
}

__global__ void bn_apply_kernel(const float* __restrict__ acc, const float* __restrict__ bnp,
                                float* __restrict__ H)
{
    const int e = blockIdx.x * blockDim.x + threadIdx.x;
    if (e >= NN * 64) return;
    const int h = e & 63;
    const float v = acc[e] * bnp[h] + bnp[64 + h];
    H[e] = v > 0.f ? v : 0.f;
}

// ---------------- generic fp32 GEMM (+bias, optional relu) ----------------
template<bool RELU>
__global__ __launch_bounds__(256)
void gemm_bias_kernel(const float* __restrict__ A, const float* __restrict__ B,
                      const float* __restrict__ bias, float* __restrict__ C,
                      int Mm, int Nn, int Kk)
{
    __shared__ float As[16][132];
    __shared__ float Bs[16][132];
    const int tx = threadIdx.x & 15, ty = threadIdx.x >> 4;
    const int m0 = blockIdx.y * 128, n0 = blockIdx.x * 128;
    float acc[8][8] = {};
    for (int k0 = 0; k0 < Kk; k0 += 16) {
        for (int e = threadIdx.x; e < 128 * 16; e += 256) {
            const int i = e >> 4, kk = e & 15;
            const int row = m0 + i, k = k0 + kk;
            As[kk][i] = (row < Mm && k < Kk) ? A[(size_t)row * Kk + k] : 0.f;
        }
        for (int e = threadIdx.x; e < 16 * 128; e += 256) {
            const int kk = e >> 7, j = e & 127;
            const int col = n0 + j, k = k0 + kk;
            Bs[kk][j] = (col < Nn && k < Kk) ? B[(size_t)k * Nn + col] : 0.f;
        }
        __syncthreads();
        #pragma unroll
        for (int kk = 0; kk < 16; ++kk) {
            float av[8], bv[8];
            #pragma unroll
            for (int i = 0; i < 8; ++i) av[i] = As[kk][ty + 16 * i];
            #pragma unroll
            for (int j = 0; j < 8; ++j) bv[j] = Bs[kk][tx + 16 * j];
            #pragma unroll
            for (int i = 0; i < 8; ++i)
                #pragma unroll
                for (int j = 0; j < 8; ++j)
                    acc[i][j] += av[i] * bv[j];
        }
        __syncthreads();
    }
    for (int i = 0; i < 8; ++i) {
        const int row = m0 + ty + 16 * i;
        if (row >= Mm) continue;
        for (int j = 0; j < 8; ++j) {
            const int col = n0 + tx + 16 * j;
            if (col >= Nn) continue;
            float v = acc[i][j] + bias[col];
            if (RELU) v = v > 0.f ? v : 0.f;
            C[(size_t)row * Nn + col] = v;
        }
    }
}

extern "C" void kernel_launch(void* const* d_in, const int* in_sizes, int n_in,
                              void* d_out, int out_size, void* d_ws, size_t ws_size,
                              hipStream_t stream)
{
    (void)in_sizes; (void)n_in; (void)out_size; (void)ws_size;
    const float* x     = (const float*)d_in[0];
    const int*   cols  = (const int*)  d_in[2];
    const float* vals  = (const float*)d_in[3];
    const float* W1    = (const float*)d_in[4];
    const float* Wc    = (const float*)d_in[5];
    // d_in[6] conv_b: zeros, and cancels in batch-stat BN regardless
    const float* gamma = (const float*)d_in[7];
    const float* beta  = (const float*)d_in[8];
    const float* fc2w  = (const float*)d_in[9];
    const float* fc2b  = (const float*)d_in[10];
    const float* fc3w  = (const float*)d_in[11];
    const float* fc3b  = (const float*)d_in[12];

    float* ws = (float*)d_ws;
    const size_t MT = (size_t)MR * 64;          // 3,527,680 floats
    float* Ta   = ws;                           // ping buffer (M x CC)
    float* Tb   = Ta + MT;                      // pong buffer
    float* part = Tb + MT;                      // per-angle partial proj [8][NN][64]
    float* acc  = part + MT;                    // summed conv output [NN][64]
    float* H    = acc + (size_t)NN * 64;        // post-BN hidden [NN][64]
    float* f2   = H + (size_t)NN * 64;          // fc2 output [NN][256]
    float* bnp  = f2 + (size_t)NN * 256;        // 128 floats: scale|shift

    for (int li = 0; li < 6; ++li) {
        const int C_in = (li == 0) ? ND : 64;
        const float* X = (li == 0) ? x : H;
        const float* W = (li == 0) ? W1 : Wc + (size_t)(li - 1) * KC * (NA * 64) * 64;
        const size_t wk = (size_t)NA * C_in * 64;    // per-k weight stride

        for (int c0 = 0; c0 < C_in; c0 += 64) {
            const int CC = (C_in - c0) >= 64 ? 64 : (C_in - c0);   // 64 or 32
            const float* W0 = W + (size_t)c0 * 64;
            if (CC == 64) {
                if (c0 == 0)
                    tile_proj_kernel<64, true ><<<NBLK, 256, 0, stream>>>(X, C_in, c0, Ta, W0, part);
                else
                    tile_proj_kernel<64, false><<<NBLK, 256, 0, stream>>>(X, C_in, c0, Ta, W0, part);
                spmm_proj_kernel<64, false><<<NBLK, 256, 0, stream>>>(Ta, Tb, cols, vals, W0 + wk, part, C_in);
                for (int k = 2; k < KC; ++k) {
                    const float* Tin = (k & 1) ? Ta : Tb;
                    float*       Tio = (k & 1) ? Tb : Ta;
                    spmm_proj_kernel<64, true><<<NBLK, 256, 0, stream>>>(Tin, Tio, cols, vals,
                                                                         W0 + (size_t)k * wk, part, C_in);
                }
            } else {
                tile_proj_kernel<32, false><<<NBLK, 256, 0, stream>>>(X, C_in, c0, Ta, W0, part);
                spmm_proj_kernel<32, false><<<NBLK, 256, 0, stream>>>(Ta, Tb, cols, vals, W0 + wk, part, C_in);
                for (int k = 2; k < KC; ++k) {
                    const float* Tin = (k & 1) ? Ta : Tb;
                    float*       Tio = (k & 1) ? Tb : Ta;
                    spmm_proj_kernel<32, true><<<NBLK, 256, 0, stream>>>(Tin, Tio, cols, vals,
                                                                         W0 + (size_t)k * wk, part, C_in);
                }
            }
        }
        bn_reduce_kernel<<<(NN * 64 + 255) / 256, 256, 0, stream>>>(part, acc);
        bn_stats_kernel<<<64, 256, 0, stream>>>(acc, gamma + li * 64, beta + li * 64, bnp);
        bn_apply_kernel<<<(NN * 64 + 255) / 256, 256, 0, stream>>>(acc, bnp, H);
    }

    // fc2: (NN x 64) @ (64 x 256) + b, relu
    gemm_bias_kernel<true ><<<dim3(2, 54),  256, 0, stream>>>(H,  fc2w, fc2b, f2, NN, 256, 64);
    // fc3: (NN x 256) @ (256 x NN) + b
    gemm_bias_kernel<false><<<dim3(54, 54), 256, 0, stream>>>(f2, fc3w, fc3b, (float*)d_out, NN, NN, 256);
}

// Round 2
// 7718.871 us; speedup vs baseline: 1.8636x; 1.8636x over previous
//
#include <hip/hip_runtime.h>
#include <cstdint>
#include <cstddef>

#define NN 6890
#define NA 8
#define KC 15
#define ND 544
#define MR (NA * NN)                 // 55120
#define DEG 16
#define BN_EPS 1e-5f

// ---------------- shared projection epilogue ----------------
// tl holds RPB rows of CC channels; each wave projects its RPW rows into
// out_part[r][h] (h = lane). Weight row index = a*C_in + c0 + cc (c0 folded
// into Wk by caller).
template<int CC, bool FIRST>
__device__ __forceinline__
void project_rows(const float (*tl)[CC + 4], const float* __restrict__ Wk,
                  float* __restrict__ out_part, int C_in, int rbase)
{
    constexpr int RPW = 64 / (CC / 4);     // rows per wave: 4 (CC=64) or 8 (CC=32)
    const int w    = threadIdx.x >> 6;
    const int lane = threadIdx.x & 63;
    const int rr0  = rbase + w * RPW;
    if (rr0 >= MR) return;
    const int tb = w * RPW;
    const int rlast = (rr0 + RPW - 1 < MR - 1) ? rr0 + RPW - 1 : MR - 1;
    const int aF = rr0 / NN, aL = rlast / NN;

    if (aF == aL && rr0 + RPW <= MR) {       // common case: one angle per wave
        const float* wp = Wk + (size_t)aF * C_in * 64 + lane;
        float o[RPW];
        #pragma unroll
        for (int i = 0; i < RPW; ++i) o[i] = 0.f;
        #pragma unroll 8
        for (int cc = 0; cc < CC; ++cc) {
            const float wv = wp[(size_t)cc * 64];
            #pragma unroll
            for (int i = 0; i < RPW; ++i) o[i] += tl[tb + i][cc] * wv;
        }
        #pragma unroll
        for (int i = 0; i < RPW; ++i) {
            const size_t idx = (size_t)(rr0 + i) * 64 + lane;
            if (FIRST) out_part[idx] = o[i];
            else       out_part[idx] += o[i];
        }
    } else {                                  // angle boundary / tail (rare)
        for (int i = 0; i < RPW; ++i) {
            const int rr = rr0 + i;
            if (rr >= MR) break;
            const int a = rr / NN;
            const float* wp = Wk + (size_t)a * C_in * 64 + lane;
            float oo = 0.f;
            for (int cc = 0; cc < CC; ++cc) oo += tl[tb + i][cc] * wp[(size_t)cc * 64];
            const size_t idx = (size_t)rr * 64 + lane;
            if (FIRST) out_part[idx] = oo;
            else       out_part[idx] += oo;
        }
    }
}

// ---------------- T0 build (tile) + projection (k=0) ----------------
template<int CC, bool FIRST>
__global__ __launch_bounds__(256)
void tile_proj_kernel(const float* __restrict__ X, int C_in, int c0,
                      float* __restrict__ Tout, const float* __restrict__ Wk,
                      float* __restrict__ out_part)
{
    constexpr int LPR = CC / 4;            // lanes per row
    constexpr int RPB = 256 / LPR;         // rows per block
    __shared__ __align__(16) float tl[RPB][CC + 4];
    const int tid  = threadIdx.x;
    const int rloc = tid / LPR, j = tid % LPR;
    const int r    = blockIdx.x * RPB + rloc;
    if (r < MR) {
        const int n = r % NN;
        const float4* X4 = (const float4*)(X + (size_t)n * C_in + c0);
        const float4 t = X4[j];
        ((float4*)Tout)[(size_t)r * LPR + j] = t;
        *(float4*)&tl[rloc][4 * j] = t;
    }
    __syncthreads();
    project_rows<CC, FIRST>(tl, Wk, out_part, C_in, blockIdx.x * RPB);
}

// ---------------- fused SpMM (+Chebyshev) + projection ----------------
// CHEB: Tio <- 2*L*Tin - Tio (in place), else Tio <- L*Tin
template<int CC, bool CHEB>
__global__ __launch_bounds__(256)
void spmm_proj_kernel(const float* __restrict__ Tin, float* __restrict__ Tio,
                      const int* __restrict__ cols, const float* __restrict__ vals,
                      const float* __restrict__ Wk, float* __restrict__ out_part,
                      int C_in)
{
    constexpr int LPR = CC / 4;
    constexpr int RPB = 256 / LPR;
    __shared__ __align__(16) float tl[RPB][CC + 4];
    const int tid  = threadIdx.x;
    const int rloc = tid / LPR, j = tid % LPR;
    const int r    = blockIdx.x * RPB + rloc;
    if (r < MR) {
        const int nz = r * DEG;
        int   ci[DEG];
        float vv[DEG];
        const int4*   c4 = (const int4*)  (cols + nz);
        const float4* v4 = (const float4*)(vals + nz);
        #pragma unroll
        for (int q = 0; q < DEG / 4; ++q) {
            *(int4*)  &ci[4 * q] = c4[q];
            *(float4*)&vv[4 * q] = v4[q];
        }
        const float4* T4 = (const float4*)Tin;
        float4 s = make_float4(0.f, 0.f, 0.f, 0.f);
        #pragma unroll
        for (int d = 0; d < DEG; ++d) {
            const float4 g = T4[(size_t)ci[d] * LPR + j];
            s.x += vv[d] * g.x; s.y += vv[d] * g.y;
            s.z += vv[d] * g.z; s.w += vv[d] * g.w;
        }
        float4* O4 = (float4*)Tio;
        float4 t;
        if (CHEB) {
            const float4 p = O4[(size_t)r * LPR + j];
            t.x = 2.f * s.x - p.x; t.y = 2.f * s.y - p.y;
            t.z = 2.f * s.z - p.z; t.w = 2.f * s.w - p.w;
        } else t = s;
        O4[(size_t)r * LPR + j] = t;
        *(float4*)&tl[rloc][4 * j] = t;
    }
    __syncthreads();
    project_rows<CC, false>(tl, Wk, out_part, C_in, blockIdx.x * RPB);
}

// ---------------- BN helpers ----------------
__global__ void bn_reduce_kernel(const float* __restrict__ part, float* __restrict__ acc)
{
    const int e = blockIdx.x * blockDim.x + threadIdx.x;
    if (e >= NN * 64) return;
    float s = 0.f;
    #pragma unroll
    for (int a = 0; a < NA; ++a) s += part[(size_t)a * NN * 64 + e];
    acc[e] = s;
}

__global__ __launch_bounds__(256)
void bn_stats_kernel(const float* __restrict__ acc, const float* __restrict__ gamma,
                     const float* __restrict__ beta, float* __restrict__ bnp)
{
    const int h = blockIdx.x;   // 64 blocks
    float s = 0.f, sq = 0.f;
    for (int n = threadIdx.x; n < NN; n += 256) {
        const float v = acc[(size_t)n * 64 + h];
        s += v; sq += v * v;
    }
    __shared__ float ls[256], lq[256];
    ls[threadIdx.x] = s; lq[threadIdx.x] = sq;
    __syncthreads();
    for (int st = 128; st > 0; st >>= 1) {
        if (threadIdx.x < st) { ls[threadIdx.x] += ls[threadIdx.x + st]; lq[threadIdx.x] += lq[threadIdx.x + st]; }
        __syncthreads();
    }
    if (threadIdx.x == 0) {
        const float mean = ls[0] / (float)NN;
        const float var  = lq[0] / (float)NN - mean * mean;
        const float sc   = gamma[h] / sqrtf(var + BN_EPS);
        bnp[h]      = sc;
        bnp[64 + h] = beta[h] - mean * sc;
    }
}

__global__ void bn_apply_kernel(const float* __restrict__ acc, const float* __restrict__ bnp,
                                float* __restrict__ H)
{
    const int e = blockIdx.x * blockDim.x + threadIdx.x;
    if (e >= NN * 64) return;
    const int h = e & 63;
    const float v = acc[e] * bnp[h] + bnp[64 + h];
    H[e] = v > 0.f ? v : 0.f;
}

// ---------------- generic fp32 GEMM (+bias, optional relu) ----------------
template<bool RELU>
__global__ __launch_bounds__(256)
void gemm_bias_kernel(const float* __restrict__ A, const float* __restrict__ B,
                      const float* __restrict__ bias, float* __restrict__ C,
                      int Mm, int Nn, int Kk)
{
    __shared__ float As[16][132];
    __shared__ float Bs[16][132];
    const int tx = threadIdx.x & 15, ty = threadIdx.x >> 4;
    const int m0 = blockIdx.y * 128, n0 = blockIdx.x * 128;
    float acc[8][8] = {};
    for (int k0 = 0; k0 < Kk; k0 += 16) {
        for (int e = threadIdx.x; e < 128 * 16; e += 256) {
            const int i = e >> 4, kk = e & 15;
            const int row = m0 + i, k = k0 + kk;
            As[kk][i] = (row < Mm && k < Kk) ? A[(size_t)row * Kk + k] : 0.f;
        }
        for (int e = threadIdx.x; e < 16 * 128; e += 256) {
            const int kk = e >> 7, j = e & 127;
            const int col = n0 + j, k = k0 + kk;
            Bs[kk][j] = (col < Nn && k < Kk) ? B[(size_t)k * Nn + col] : 0.f;
        }
        __syncthreads();
        #pragma unroll
        for (int kk = 0; kk < 16; ++kk) {
            float av[8], bv[8];
            #pragma unroll
            for (int i = 0; i < 8; ++i) av[i] = As[kk][ty + 16 * i];
            #pragma unroll
            for (int j = 0; j < 8; ++j) bv[j] = Bs[kk][tx + 16 * j];
            #pragma unroll
            for (int i = 0; i < 8; ++i)
                #pragma unroll
                for (int j = 0; j < 8; ++j)
                    acc[i][j] += av[i] * bv[j];
        }
        __syncthreads();
    }
    for (int i = 0; i < 8; ++i) {
        const int row = m0 + ty + 16 * i;
        if (row >= Mm) continue;
        for (int j = 0; j < 8; ++j) {
            const int col = n0 + tx + 16 * j;
            if (col >= Nn) continue;
            float v = acc[i][j] + bias[col];
            if (RELU) v = v > 0.f ? v : 0.f;
            C[(size_t)row * Nn + col] = v;
        }
    }
}

extern "C" void kernel_launch(void* const* d_in, const int* in_sizes, int n_in,
                              void* d_out, int out_size, void* d_ws, size_t ws_size,
                              hipStream_t stream)
{
    (void)in_sizes; (void)n_in; (void)out_size; (void)ws_size;
    const float* x     = (const float*)d_in[0];
    const int*   cols  = (const int*)  d_in[2];
    const float* vals  = (const float*)d_in[3];
    const float* W1    = (const float*)d_in[4];
    const float* Wc    = (const float*)d_in[5];
    const float* gamma = (const float*)d_in[7];
    const float* beta  = (const float*)d_in[8];
    const float* fc2w  = (const float*)d_in[9];
    const float* fc2b  = (const float*)d_in[10];
    const float* fc3w  = (const float*)d_in[11];
    const float* fc3b  = (const float*)d_in[12];

    float* ws = (float*)d_ws;
    const size_t MT = (size_t)MR * 64;
    float* Ta   = ws;
    float* Tb   = Ta + MT;
    float* part = Tb + MT;                      // [8][NN][64]
    float* acc  = part + MT;                    // [NN][64]
    float* H    = acc + (size_t)NN * 64;        // [NN][64]
    float* f2   = H + (size_t)NN * 64;          // [NN][256]
    float* bnp  = f2 + (size_t)NN * 256;        // 128 floats

    const int NB64 = MR / 16;                   // 3445 (exact)
    const int NB32 = (MR + 31) / 32;            // 1723

    for (int li = 0; li < 6; ++li) {
        const int C_in = (li == 0) ? ND : 64;
        const float* X = (li == 0) ? x : H;
        const float* W = (li == 0) ? W1 : Wc + (size_t)(li - 1) * KC * (NA * 64) * 64;
        const size_t wk = (size_t)NA * C_in * 64;

        for (int c0 = 0; c0 < C_in; c0 += 64) {
            const int CC = (C_in - c0) >= 64 ? 64 : (C_in - c0);
            const float* W0 = W + (size_t)c0 * 64;
            if (CC == 64) {
                if (c0 == 0)
                    tile_proj_kernel<64, true ><<<NB64, 256, 0, stream>>>(X, C_in, c0, Ta, W0, part);
                else
                    tile_proj_kernel<64, false><<<NB64, 256, 0, stream>>>(X, C_in, c0, Ta, W0, part);
                spmm_proj_kernel<64, false><<<NB64, 256, 0, stream>>>(Ta, Tb, cols, vals, W0 + wk, part, C_in);
                for (int k = 2; k < KC; ++k) {
                    const float* Tin = (k & 1) ? Ta : Tb;
                    float*       Tio = (k & 1) ? Tb : Ta;
                    spmm_proj_kernel<64, true><<<NB64, 256, 0, stream>>>(Tin, Tio, cols, vals,
                                                                         W0 + (size_t)k * wk, part, C_in);
                }
            } else {
                tile_proj_kernel<32, false><<<NB32, 256, 0, stream>>>(X, C_in, c0, Ta, W0, part);
                spmm_proj_kernel<32, false><<<NB32, 256, 0, stream>>>(Ta, Tb, cols, vals, W0 + wk, part, C_in);
                for (int k = 2; k < KC; ++k) {
                    const float* Tin = (k & 1) ? Ta : Tb;
                    float*       Tio = (k & 1) ? Tb : Ta;
                    spmm_proj_kernel<32, true><<<NB32, 256, 0, stream>>>(Tin, Tio, cols, vals,
                                                                         W0 + (size_t)k * wk, part, C_in);
                }
            }
        }
        bn_reduce_kernel<<<(NN * 64 + 255) / 256, 256, 0, stream>>>(part, acc);
        bn_stats_kernel<<<64, 256, 0, stream>>>(acc, gamma + li * 64, beta + li * 64, bnp);
        bn_apply_kernel<<<(NN * 64 + 255) / 256, 256, 0, stream>>>(acc, bnp, H);
    }

    gemm_bias_kernel<true ><<<dim3(2, 54),  256, 0, stream>>>(H,  fc2w, fc2b, f2, NN, 256, 64);
    gemm_bias_kernel<false><<<dim3(54, 54), 256, 0, stream>>>(f2, fc3w, fc3b, (float*)d_out, NN, NN, 256);
}

// Round 3
// 6032.327 us; speedup vs baseline: 2.3847x; 1.2796x over previous
//
#include <hip/hip_runtime.h>
#include <cstdint>
#include <cstddef>

#define NN 6890
#define NA 8
#define KC 15
#define ND 544
#define MR (NA * NN)                 // 55120
#define DEG 16
#define BN_EPS 1e-5f

typedef unsigned int u32;

__device__ __forceinline__ float blo(u32 u) { return __uint_as_float(u << 16); }
__device__ __forceinline__ float bhi(u32 u) { return __uint_as_float(u & 0xffff0000u); }
__device__ __forceinline__ u32 brnd(float f) {   // fp32 -> bf16 bits (RNE), in low 16
    u32 u = __float_as_uint(f);
    return (u + 0x7fffu + ((u >> 16) & 1u)) >> 16;
}
__device__ __forceinline__ u32 pack2(float a, float b) {
    return brnd(a) | (brnd(b) << 16);
}

// ---------------- shared projection epilogue ----------------
// tl holds RPB rows x CC fp32 channels; wave w projects its RPW rows into
// out_part[r][h] (h = lane).
template<int CC, bool FIRST>
__device__ __forceinline__
void project_rows(const float (*tl)[CC + 4], const float* __restrict__ Wk,
                  float* __restrict__ out_part, int C_in, int rbase)
{
    constexpr int LPR = CC / 8;
    constexpr int RPB = 256 / LPR;
    constexpr int RPW = RPB / 4;
    const int w    = threadIdx.x >> 6;
    const int lane = threadIdx.x & 63;
    const int rr0  = rbase + w * RPW;
    if (rr0 >= MR) return;
    const int tb = w * RPW;
    const int rlast = (rr0 + RPW - 1 < MR - 1) ? rr0 + RPW - 1 : MR - 1;
    const int aF = rr0 / NN, aL = rlast / NN;

    if (aF == aL && rr0 + RPW <= MR) {       // common: one angle per wave
        const float* wp = Wk + (size_t)aF * C_in * 64 + lane;
        float o[RPW];
        #pragma unroll
        for (int i = 0; i < RPW; ++i) o[i] = 0.f;
        #pragma unroll 8
        for (int cc = 0; cc < CC; ++cc) {
            const float wv = wp[(size_t)cc * 64];
            #pragma unroll
            for (int i = 0; i < RPW; ++i) o[i] += tl[tb + i][cc] * wv;
        }
        #pragma unroll
        for (int i = 0; i < RPW; ++i) {
            const size_t idx = (size_t)(rr0 + i) * 64 + lane;
            if (FIRST) out_part[idx] = o[i];
            else       out_part[idx] += o[i];
        }
    } else {                                  // angle boundary / tail
        for (int i = 0; i < RPW; ++i) {
            const int rr = rr0 + i;
            if (rr >= MR) break;
            const int a = rr / NN;
            const float* wp = Wk + (size_t)a * C_in * 64 + lane;
            float oo = 0.f;
            for (int cc = 0; cc < CC; ++cc) oo += tl[tb + i][cc] * wp[(size_t)cc * 64];
            const size_t idx = (size_t)rr * 64 + lane;
            if (FIRST) out_part[idx] = oo;
            else       out_part[idx] += oo;
        }
    }
}

// ---------------- T0 build + projection (k=0) ----------------
template<int CC, bool FIRST, bool MIX>
__global__ __launch_bounds__(256)
void tile_proj_kernel(const float* __restrict__ X, int C_in, int c0,
                      float* __restrict__ Fout, u32* __restrict__ Mout,
                      const float* __restrict__ Wk, float* __restrict__ out_part)
{
    constexpr int LPR = CC / 8;
    constexpr int RPB = 256 / LPR;
    __shared__ __align__(16) float tl[RPB][CC + 4];
    const int tid  = threadIdx.x;
    const int rloc = tid / LPR, j = tid % LPR;
    const int r    = blockIdx.x * RPB + rloc;
    if (r < MR) {
        const int n = r % NN;
        const float4 t0 = *(const float4*)&X[(size_t)n * C_in + c0 + 8 * j];
        const float4 t1 = *(const float4*)&X[(size_t)n * C_in + c0 + 8 * j + 4];
        if (MIX) {
            ((float4*)Fout)[(size_t)r * (CC / 4) + 2 * j]     = t0;
            ((float4*)Fout)[(size_t)r * (CC / 4) + 2 * j + 1] = t1;
        }
        uint4 m;
        m.x = pack2(t0.x, t0.y); m.y = pack2(t0.z, t0.w);
        m.z = pack2(t1.x, t1.y); m.w = pack2(t1.z, t1.w);
        ((uint4*)Mout)[(size_t)r * LPR + j] = m;
        *(float4*)&tl[rloc][8 * j]     = t0;
        *(float4*)&tl[rloc][8 * j + 4] = t1;
    }
    __syncthreads();
    project_rows<CC, FIRST>(tl, Wk, out_part, C_in, blockIdx.x * RPB);
}

// ---------------- fused SpMM (+Chebyshev) + projection ----------------
// MIX:  recurrence state fp32 in Fio, gathers read bf16 mirror Min, write Mio
// !MIX: recurrence state entirely in bf16 mirrors
template<int CC, bool CHEB, bool MIX>
__global__ __launch_bounds__(256)
void spmm_proj_kernel(const u32* __restrict__ Min, float* __restrict__ Fio,
                      u32* __restrict__ Mio,
                      const int* __restrict__ cols, const float* __restrict__ vals,
                      const float* __restrict__ Wk, float* __restrict__ out_part,
                      int C_in)
{
    constexpr int LPR = CC / 8;
    constexpr int RPB = 256 / LPR;
    __shared__ __align__(16) float tl[RPB][CC + 4];
    const int tid  = threadIdx.x;
    const int rloc = tid / LPR, j = tid % LPR;
    const int r    = blockIdx.x * RPB + rloc;
    if (r < MR) {
        const int nz = r * DEG;
        int   ci[DEG];
        float vv[DEG];
        const int4*   c4 = (const int4*)  (cols + nz);
        const float4* v4 = (const float4*)(vals + nz);
        #pragma unroll
        for (int q = 0; q < DEG / 4; ++q) {
            *(int4*)  &ci[4 * q] = c4[q];
            *(float4*)&vv[4 * q] = v4[q];
        }
        const uint4* M4 = (const uint4*)Min;
        float s[8] = {0.f, 0.f, 0.f, 0.f, 0.f, 0.f, 0.f, 0.f};
        #pragma unroll
        for (int d = 0; d < DEG; ++d) {
            const uint4 g = M4[(size_t)ci[d] * LPR + j];
            const float v = vv[d];
            s[0] += v * blo(g.x); s[1] += v * bhi(g.x);
            s[2] += v * blo(g.y); s[3] += v * bhi(g.y);
            s[4] += v * blo(g.z); s[5] += v * bhi(g.z);
            s[6] += v * blo(g.w); s[7] += v * bhi(g.w);
        }
        float t[8];
        if (CHEB) {
            if (MIX) {
                const float4 p0 = ((const float4*)Fio)[(size_t)r * (CC / 4) + 2 * j];
                const float4 p1 = ((const float4*)Fio)[(size_t)r * (CC / 4) + 2 * j + 1];
                t[0] = 2.f * s[0] - p0.x; t[1] = 2.f * s[1] - p0.y;
                t[2] = 2.f * s[2] - p0.z; t[3] = 2.f * s[3] - p0.w;
                t[4] = 2.f * s[4] - p1.x; t[5] = 2.f * s[5] - p1.y;
                t[6] = 2.f * s[6] - p1.z; t[7] = 2.f * s[7] - p1.w;
            } else {
                const uint4 p = ((const uint4*)Mio)[(size_t)r * LPR + j];
                t[0] = 2.f * s[0] - blo(p.x); t[1] = 2.f * s[1] - bhi(p.x);
                t[2] = 2.f * s[2] - blo(p.y); t[3] = 2.f * s[3] - bhi(p.y);
                t[4] = 2.f * s[4] - blo(p.z); t[5] = 2.f * s[5] - bhi(p.z);
                t[6] = 2.f * s[6] - blo(p.w); t[7] = 2.f * s[7] - bhi(p.w);
            }
        } else {
            #pragma unroll
            for (int i = 0; i < 8; ++i) t[i] = s[i];
        }
        if (MIX) {
            ((float4*)Fio)[(size_t)r * (CC / 4) + 2 * j]     = make_float4(t[0], t[1], t[2], t[3]);
            ((float4*)Fio)[(size_t)r * (CC / 4) + 2 * j + 1] = make_float4(t[4], t[5], t[6], t[7]);
        }
        uint4 m;
        m.x = pack2(t[0], t[1]); m.y = pack2(t[2], t[3]);
        m.z = pack2(t[4], t[5]); m.w = pack2(t[6], t[7]);
        ((uint4*)Mio)[(size_t)r * LPR + j] = m;
        *(float4*)&tl[rloc][8 * j]     = make_float4(t[0], t[1], t[2], t[3]);
        *(float4*)&tl[rloc][8 * j + 4] = make_float4(t[4], t[5], t[6], t[7]);
    }
    __syncthreads();
    project_rows<CC, false>(tl, Wk, out_part, C_in, blockIdx.x * RPB);
}

// ---------------- BN helpers ----------------
__global__ void bn_reduce_kernel(const float* __restrict__ part, float* __restrict__ acc)
{
    const int e = blockIdx.x * blockDim.x + threadIdx.x;
    if (e >= NN * 64) return;
    float s = 0.f;
    #pragma unroll
    for (int a = 0; a < NA; ++a) s += part[(size_t)a * NN * 64 + e];
    acc[e] = s;
}

__global__ __launch_bounds__(256)
void bn_stats_kernel(const float* __restrict__ acc, const float* __restrict__ gamma,
                     const float* __restrict__ beta, float* __restrict__ bnp)
{
    const int h = blockIdx.x;   // 64 blocks
    float s = 0.f, sq = 0.f;
    for (int n = threadIdx.x; n < NN; n += 256) {
        const float v = acc[(size_t)n * 64 + h];
        s += v; sq += v * v;
    }
    __shared__ float ls[256], lq[256];
    ls[threadIdx.x] = s; lq[threadIdx.x] = sq;
    __syncthreads();
    for (int st = 128; st > 0; st >>= 1) {
        if (threadIdx.x < st) { ls[threadIdx.x] += ls[threadIdx.x + st]; lq[threadIdx.x] += lq[threadIdx.x + st]; }
        __syncthreads();
    }
    if (threadIdx.x == 0) {
        const float mean = ls[0] / (float)NN;
        const float var  = lq[0] / (float)NN - mean * mean;
        const float sc   = gamma[h] / sqrtf(var + BN_EPS);
        bnp[h]      = sc;
        bnp[64 + h] = beta[h] - mean * sc;
    }
}

__global__ void bn_apply_kernel(const float* __restrict__ acc, const float* __restrict__ bnp,
                                float* __restrict__ H)
{
    const int e = blockIdx.x * blockDim.x + threadIdx.x;
    if (e >= NN * 64) return;
    const int h = e & 63;
    const float v = acc[e] * bnp[h] + bnp[64 + h];
    H[e] = v > 0.f ? v : 0.f;
}

// ---------------- fp32 GEMM (+bias, optional relu), 8-contig tiles ----------------
template<bool RELU>
__global__ __launch_bounds__(256)
void gemm_bias_kernel(const float* __restrict__ A, const float* __restrict__ B,
                      const float* __restrict__ bias, float* __restrict__ C,
                      int Mm, int Nn, int Kk)
{
    __shared__ float As[16][132];
    __shared__ float Bs[16][132];
    const int tx = threadIdx.x & 15, ty = threadIdx.x >> 4;
    const int m0 = blockIdx.y * 128, n0 = blockIdx.x * 128;
    const bool full = (m0 + 128 <= Mm) && (n0 + 128 <= Nn);
    float acc[8][8] = {};
    for (int k0 = 0; k0 < Kk; k0 += 16) {
        if (full) {
            #pragma unroll
            for (int e = threadIdx.x; e < 512; e += 256) {
                const int i = e >> 2, q = e & 3;
                const float4 a4 = *(const float4*)&A[(size_t)(m0 + i) * Kk + k0 + 4 * q];
                As[4 * q + 0][i] = a4.x; As[4 * q + 1][i] = a4.y;
                As[4 * q + 2][i] = a4.z; As[4 * q + 3][i] = a4.w;
            }
            #pragma unroll
            for (int e = threadIdx.x; e < 512; e += 256) {
                const int kk = e >> 5, q = e & 31;
                *(float4*)&Bs[kk][4 * q] = *(const float4*)&B[(size_t)(k0 + kk) * Nn + n0 + 4 * q];
            }
        } else {
            for (int e = threadIdx.x; e < 128 * 16; e += 256) {
                const int i = e >> 4, kk = e & 15;
                const int row = m0 + i;
                As[kk][i] = (row < Mm) ? A[(size_t)row * Kk + k0 + kk] : 0.f;
            }
            for (int e = threadIdx.x; e < 16 * 128; e += 256) {
                const int kk = e >> 7, jj = e & 127;
                const int col = n0 + jj;
                Bs[kk][jj] = (col < Nn) ? B[(size_t)(k0 + kk) * Nn + col] : 0.f;
            }
        }
        __syncthreads();
        #pragma unroll
        for (int kk = 0; kk < 16; ++kk) {
            float av[8], bv[8];
            *(float4*)&av[0] = *(const float4*)&As[kk][ty * 8];
            *(float4*)&av[4] = *(const float4*)&As[kk][ty * 8 + 4];
            *(float4*)&bv[0] = *(const float4*)&Bs[kk][tx * 8];
            *(float4*)&bv[4] = *(const float4*)&Bs[kk][tx * 8 + 4];
            #pragma unroll
            for (int i = 0; i < 8; ++i)
                #pragma unroll
                for (int jj = 0; jj < 8; ++jj)
                    acc[i][jj] += av[i] * bv[jj];
        }
        __syncthreads();
    }
    if (full) {
        float4 b0 = *(const float4*)&bias[n0 + tx * 8];
        float4 b1 = *(const float4*)&bias[n0 + tx * 8 + 4];
        #pragma unroll
        for (int i = 0; i < 8; ++i) {
            const int row = m0 + ty * 8 + i;
            float4 v0 = make_float4(acc[i][0] + b0.x, acc[i][1] + b0.y,
                                    acc[i][2] + b0.z, acc[i][3] + b0.w);
            float4 v1 = make_float4(acc[i][4] + b1.x, acc[i][5] + b1.y,
                                    acc[i][6] + b1.z, acc[i][7] + b1.w);
            if (RELU) {
                v0.x = fmaxf(v0.x, 0.f); v0.y = fmaxf(v0.y, 0.f);
                v0.z = fmaxf(v0.z, 0.f); v0.w = fmaxf(v0.w, 0.f);
                v1.x = fmaxf(v1.x, 0.f); v1.y = fmaxf(v1.y, 0.f);
                v1.z = fmaxf(v1.z, 0.f); v1.w = fmaxf(v1.w, 0.f);
            }
            *(float4*)&C[(size_t)row * Nn + n0 + tx * 8]     = v0;
            *(float4*)&C[(size_t)row * Nn + n0 + tx * 8 + 4] = v1;
        }
    } else {
        for (int i = 0; i < 8; ++i) {
            const int row = m0 + ty * 8 + i;
            if (row >= Mm) continue;
            for (int jj = 0; jj < 8; ++jj) {
                const int col = n0 + tx * 8 + jj;
                if (col >= Nn) continue;
                float v = acc[i][jj] + bias[col];
                if (RELU) v = fmaxf(v, 0.f);
                C[(size_t)row * Nn + col] = v;
            }
        }
    }
}

// ---------------- conv-stack driver (templated on MIX) ----------------
template<bool MIX>
static void run_convs(const float* x, const int* cols, const float* vals,
                      const float* W1, const float* Wc,
                      const float* gamma, const float* beta,
                      float* Fa, float* Fb, u32* Ma, u32* Mb, float* part,
                      float* acc, float* H, float* bnp, hipStream_t stream)
{
    const int NB64 = (MR + 31) / 32;   // 1723
    const int NB32 = (MR + 63) / 64;   // 862
    for (int li = 0; li < 6; ++li) {
        const int C_in = (li == 0) ? ND : 64;
        const float* X = (li == 0) ? x : H;
        const float* W = (li == 0) ? W1 : Wc + (size_t)(li - 1) * KC * (NA * 64) * 64;
        const size_t wk = (size_t)NA * C_in * 64;
        for (int c0 = 0; c0 < C_in; c0 += 64) {
            const int CC = (C_in - c0) >= 64 ? 64 : 32;
            const float* W0 = W + (size_t)c0 * 64;
            if (CC == 64) {
                if (c0 == 0)
                    tile_proj_kernel<64, true , MIX><<<NB64, 256, 0, stream>>>(X, C_in, c0, Fa, Ma, W0, part);
                else
                    tile_proj_kernel<64, false, MIX><<<NB64, 256, 0, stream>>>(X, C_in, c0, Fa, Ma, W0, part);
                spmm_proj_kernel<64, false, MIX><<<NB64, 256, 0, stream>>>(Ma, Fb, Mb, cols, vals, W0 + wk, part, C_in);
                for (int k = 2; k < KC; ++k) {
                    const u32* Min = (k & 1) ? Ma : Mb;
                    float*     Fio = (k & 1) ? Fb : Fa;
                    u32*       Mio = (k & 1) ? Mb : Ma;
                    spmm_proj_kernel<64, true, MIX><<<NB64, 256, 0, stream>>>(Min, Fio, Mio, cols, vals,
                                                                              W0 + (size_t)k * wk, part, C_in);
                }
            } else {
                tile_proj_kernel<32, false, MIX><<<NB32, 256, 0, stream>>>(X, C_in, c0, Fa, Ma, W0, part);
                spmm_proj_kernel<32, false, MIX><<<NB32, 256, 0, stream>>>(Ma, Fb, Mb, cols, vals, W0 + wk, part, C_in);
                for (int k = 2; k < KC; ++k) {
                    const u32* Min = (k & 1) ? Ma : Mb;
                    float*     Fio = (k & 1) ? Fb : Fa;
                    u32*       Mio = (k & 1) ? Mb : Ma;
                    spmm_proj_kernel<32, true, MIX><<<NB32, 256, 0, stream>>>(Min, Fio, Mio, cols, vals,
                                                                              W0 + (size_t)k * wk, part, C_in);
                }
            }
        }
        bn_reduce_kernel<<<(NN * 64 + 255) / 256, 256, 0, stream>>>(part, acc);
        bn_stats_kernel<<<64, 256, 0, stream>>>(acc, gamma + li * 64, beta + li * 64, bnp);
        bn_apply_kernel<<<(NN * 64 + 255) / 256, 256, 0, stream>>>(acc, bnp, H);
    }
}

extern "C" void kernel_launch(void* const* d_in, const int* in_sizes, int n_in,
                              void* d_out, int out_size, void* d_ws, size_t ws_size,
                              hipStream_t stream)
{
    (void)in_sizes; (void)n_in; (void)out_size;
    const float* x     = (const float*)d_in[0];
    const int*   cols  = (const int*)  d_in[2];
    const float* vals  = (const float*)d_in[3];
    const float* W1    = (const float*)d_in[4];
    const float* Wc    = (const float*)d_in[5];
    const float* gamma = (const float*)d_in[7];
    const float* beta  = (const float*)d_in[8];
    const float* fc2w  = (const float*)d_in[9];
    const float* fc2b  = (const float*)d_in[10];
    const float* fc3w  = (const float*)d_in[11];
    const float* fc3b  = (const float*)d_in[12];

    const size_t MT = (size_t)MR * 64;
    const size_t need_mix = 2 * MT * 4      // Fa, Fb fp32
                          + 2 * MT * 2      // Ma, Mb bf16 mirrors
                          + MT * 4          // part
                          + (size_t)NN * 64 * 4 * 2
                          + (size_t)NN * 256 * 4 + 1024;
    const bool mix = ws_size >= need_mix;

    char* base = (char*)d_ws;
    size_t off = 0;
    float* Fa = nullptr; float* Fb = nullptr;
    if (mix) { Fa = (float*)(base + off); off += MT * 4;
               Fb = (float*)(base + off); off += MT * 4; }
    u32* Ma = (u32*)(base + off); off += MT * 2;
    u32* Mb = (u32*)(base + off); off += MT * 2;
    float* part = (float*)(base + off); off += MT * 4;
    float* acc  = (float*)(base + off); off += (size_t)NN * 64 * 4;
    float* H    = (float*)(base + off); off += (size_t)NN * 64 * 4;
    float* f2   = (float*)(base + off); off += (size_t)NN * 256 * 4;
    float* bnp  = (float*)(base + off);

    if (mix)
        run_convs<true >(x, cols, vals, W1, Wc, gamma, beta, Fa, Fb, Ma, Mb, part, acc, H, bnp, stream);
    else
        run_convs<false>(x, cols, vals, W1, Wc, gamma, beta, Fa, Fb, Ma, Mb, part, acc, H, bnp, stream);

    gemm_bias_kernel<true ><<<dim3(2, 54),  256, 0, stream>>>(H,  fc2w, fc2b, f2, NN, 256, 64);
    gemm_bias_kernel<false><<<dim3(54, 54), 256, 0, stream>>>(f2, fc3w, fc3b, (float*)d_out, NN, NN, 256);
}

// Round 5
// 5985.645 us; speedup vs baseline: 2.4033x; 1.0078x over previous
//
#include <hip/hip_runtime.h>
#include <hip/hip_cooperative_groups.h>
#include <cstdint>
#include <cstddef>

namespace cg = cooperative_groups;

#define NN 6890
#define NA 8
#define KC 15
#define ND 544
#define MR (NA * NN)                 // 55120
#define DEG 16
#define BN_EPS 1e-5f
#define BPA 108                      // blocks-per-angle worth of 64-row groups
#define GROUPS (NA * BPA)            // 864
#define CBLK (GROUPS / 2)            // 432 cooperative blocks, 2 groups each

typedef unsigned int u32;

__device__ __forceinline__ float blo(u32 u) { return __uint_as_float(u << 16); }
__device__ __forceinline__ float bhi(u32 u) { return __uint_as_float(u & 0xffff0000u); }
__device__ __forceinline__ u32 brnd(float f) {   // fp32 -> bf16 bits (RNE)
    u32 u = __float_as_uint(f);
    return (u + 0x7fffu + ((u >> 16) & 1u)) >> 16;
}
__device__ __forceinline__ u32 pack2(float a, float b) {
    return brnd(a) | (brnd(b) << 16);
}
__device__ __forceinline__ void acc8(float* s, float v, uint4 g) {
    s[0] += v * blo(g.x); s[1] += v * bhi(g.x);
    s[2] += v * blo(g.y); s[3] += v * bhi(g.y);
    s[4] += v * blo(g.z); s[5] += v * bhi(g.z);
    s[6] += v * blo(g.w); s[7] += v * bhi(g.w);
}

// ================= fused cooperative conv (full k-loop, 2 groups/block) ==========
template<int CC, int RPT, int STR, int LPR>
__device__ __forceinline__
void cheb_step(int k, int a, int n0b, const float* __restrict__ X, int C_in, int c0,
               const int* __restrict__ cols, const float* __restrict__ vals,
               const u32* __restrict__ Mprev, u32* __restrict__ Mw,
               float (&T0f)[RPT][8], float (&T1f)[RPT][8],
               float (*tl)[CC + 4], int j, int rloc)
{
    #pragma unroll
    for (int s = 0; s < RPT; ++s) {
        const int n = n0b + s * STR + rloc;
        float tn[8];
        if (k == 0) {
            if (n < NN) {
                const float4 t0 = *(const float4*)&X[(size_t)n * C_in + c0 + 8 * j];
                const float4 t1 = *(const float4*)&X[(size_t)n * C_in + c0 + 8 * j + 4];
                tn[0] = t0.x; tn[1] = t0.y; tn[2] = t0.z; tn[3] = t0.w;
                tn[4] = t1.x; tn[5] = t1.y; tn[6] = t1.z; tn[7] = t1.w;
            } else {
                #pragma unroll
                for (int c = 0; c < 8; ++c) tn[c] = 0.f;
            }
        } else {
            float sg[8] = {0.f, 0.f, 0.f, 0.f, 0.f, 0.f, 0.f, 0.f};
            if (n < NN) {
                const int r = a * NN + n;
                const uint4*  M4 = (const uint4*)Mprev;
                const int4*   c4 = (const int4*)  (cols + r * DEG);
                const float4* v4 = (const float4*)(vals + r * DEG);
                #pragma unroll
                for (int q = 0; q < 4; ++q) {
                    const int4   ci = c4[q];
                    const float4 vv = v4[q];
                    const uint4 g0 = M4[(size_t)ci.x * LPR + j];
                    const uint4 g1 = M4[(size_t)ci.y * LPR + j];
                    const uint4 g2 = M4[(size_t)ci.z * LPR + j];
                    const uint4 g3 = M4[(size_t)ci.w * LPR + j];
                    acc8(sg, vv.x, g0); acc8(sg, vv.y, g1);
                    acc8(sg, vv.z, g2); acc8(sg, vv.w, g3);
                }
            }
            if (k == 1) {
                #pragma unroll
                for (int c = 0; c < 8; ++c) tn[c] = sg[c];
            } else {
                #pragma unroll
                for (int c = 0; c < 8; ++c) tn[c] = 2.f * sg[c] - T0f[s][c];
            }
        }
        #pragma unroll
        for (int c = 0; c < 8; ++c) { T0f[s][c] = T1f[s][c]; T1f[s][c] = tn[c]; }
        if (n < NN) {
            uint4 m;
            m.x = pack2(tn[0], tn[1]); m.y = pack2(tn[2], tn[3]);
            m.z = pack2(tn[4], tn[5]); m.w = pack2(tn[6], tn[7]);
            ((uint4*)Mw)[(size_t)(a * NN + n) * LPR + j] = m;
        }
        *(float4*)&tl[s * STR + rloc][8 * j]     = make_float4(tn[0], tn[1], tn[2], tn[3]);
        *(float4*)&tl[s * STR + rloc][8 * j + 4] = make_float4(tn[4], tn[5], tn[6], tn[7]);
    }
}

template<int CC>
__device__ __forceinline__
void proj_step(const float (*tl)[CC + 4], const float* __restrict__ wp,
               float (&oacc)[16], int w)
{
    const int rw0 = w * 16;
    #pragma unroll 2
    for (int cc4 = 0; cc4 < CC / 4; ++cc4) {
        const float w0 = wp[(size_t)(cc4 * 4 + 0) * 64];
        const float w1 = wp[(size_t)(cc4 * 4 + 1) * 64];
        const float w2 = wp[(size_t)(cc4 * 4 + 2) * 64];
        const float w3 = wp[(size_t)(cc4 * 4 + 3) * 64];
        #pragma unroll
        for (int i = 0; i < 16; ++i) {
            const float4 t4 = *(const float4*)&tl[rw0 + i][cc4 * 4];
            oacc[i] += t4.x * w0 + t4.y * w1 + t4.z * w2 + t4.w * w3;
        }
    }
}

template<int CC, bool FIRST>
__global__ __launch_bounds__(256, 2)
void conv_fused_kernel(const float* __restrict__ X, int C_in, int c0,
                       const int* __restrict__ cols, const float* __restrict__ vals,
                       const float* __restrict__ W,
                       float* __restrict__ part,
                       u32* __restrict__ Ma, u32* __restrict__ Mb)
{
    constexpr int LPR = CC / 8;
    constexpr int STR = 256 / LPR;
    constexpr int RPT = 64 / STR;

    __shared__ __align__(16) float tl[64][CC + 4];

    const int tid  = threadIdx.x;
    const int j    = tid % LPR;
    const int rloc = tid / LPR;
    const int lane = tid & 63;
    const int w    = tid >> 6;
    const size_t wk = (size_t)NA * C_in * 64;

    const int gA = blockIdx.x, gB = blockIdx.x + CBLK;
    const int aA = gA / BPA, n0A = (gA % BPA) * 64;
    const int aB = gB / BPA, n0B = (gB % BPA) * 64;
    const float* WA = W + ((size_t)aA * C_in + c0) * 64 + lane;
    const float* WB = W + ((size_t)aB * C_in + c0) * 64 + lane;

    float T0A[RPT][8], T1A[RPT][8], T0B[RPT][8], T1B[RPT][8];
    float oA[16], oB[16];
    #pragma unroll
    for (int i = 0; i < 16; ++i) { oA[i] = 0.f; oB[i] = 0.f; }
    #pragma unroll
    for (int s = 0; s < RPT; ++s)
        #pragma unroll
        for (int c = 0; c < 8; ++c) {
            T0A[s][c] = 0.f; T1A[s][c] = 0.f;
            T0B[s][c] = 0.f; T1B[s][c] = 0.f;
        }

    cg::grid_group grid = cg::this_grid();

    for (int k = 0; k < KC; ++k) {
        if (k) { __threadfence(); grid.sync(); __threadfence(); }
        const u32* Mprev = ((k - 1) & 1) ? Mb : Ma;
        u32*       Mw    = (k & 1) ? Mb : Ma;

        cheb_step<CC, RPT, STR, LPR>(k, aA, n0A, X, C_in, c0, cols, vals,
                                     Mprev, Mw, T0A, T1A, tl, j, rloc);
        __syncthreads();
        proj_step<CC>(tl, WA + (size_t)k * wk, oA, w);
        __syncthreads();
        cheb_step<CC, RPT, STR, LPR>(k, aB, n0B, X, C_in, c0, cols, vals,
                                     Mprev, Mw, T0B, T1B, tl, j, rloc);
        __syncthreads();
        proj_step<CC>(tl, WB + (size_t)k * wk, oB, w);
        __syncthreads();
    }

    #pragma unroll
    for (int i = 0; i < 16; ++i) {
        const int nA = n0A + w * 16 + i;
        if (nA < NN) {
            const size_t idx = ((size_t)aA * NN + nA) * 64 + lane;
            if (FIRST) part[idx] = oA[i]; else part[idx] += oA[i];
        }
        const int nB = n0B + w * 16 + i;
        if (nB < NN) {
            const size_t idx = ((size_t)aB * NN + nB) * 64 + lane;
            if (FIRST) part[idx] = oB[i]; else part[idx] += oB[i];
        }
    }
}

// ================= fallback: round-3 per-k kernels (proven correct) ==============
template<int CC, bool FIRST>
__device__ __forceinline__
void project_rows(const float (*tl)[CC + 4], const float* __restrict__ Wk,
                  float* __restrict__ out_part, int C_in, int rbase)
{
    constexpr int LPR = CC / 8;
    constexpr int RPB = 256 / LPR;
    constexpr int RPW = RPB / 4;
    const int w    = threadIdx.x >> 6;
    const int lane = threadIdx.x & 63;
    const int rr0  = rbase + w * RPW;
    if (rr0 >= MR) return;
    const int tb = w * RPW;
    const int rlast = (rr0 + RPW - 1 < MR - 1) ? rr0 + RPW - 1 : MR - 1;
    const int aF = rr0 / NN, aL = rlast / NN;

    if (aF == aL && rr0 + RPW <= MR) {
        const float* wp = Wk + (size_t)aF * C_in * 64 + lane;
        float o[RPW];
        #pragma unroll
        for (int i = 0; i < RPW; ++i) o[i] = 0.f;
        #pragma unroll 8
        for (int cc = 0; cc < CC; ++cc) {
            const float wv = wp[(size_t)cc * 64];
            #pragma unroll
            for (int i = 0; i < RPW; ++i) o[i] += tl[tb + i][cc] * wv;
        }
        #pragma unroll
        for (int i = 0; i < RPW; ++i) {
            const size_t idx = (size_t)(rr0 + i) * 64 + lane;
            if (FIRST) out_part[idx] = o[i];
            else       out_part[idx] += o[i];
        }
    } else {
        for (int i = 0; i < RPW; ++i) {
            const int rr = rr0 + i;
            if (rr >= MR) break;
            const int a = rr / NN;
            const float* wp = Wk + (size_t)a * C_in * 64 + lane;
            float oo = 0.f;
            for (int cc = 0; cc < CC; ++cc) oo += tl[tb + i][cc] * wp[(size_t)cc * 64];
            const size_t idx = (size_t)rr * 64 + lane;
            if (FIRST) out_part[idx] = oo;
            else       out_part[idx] += oo;
        }
    }
}

template<int CC, bool FIRST>
__global__ __launch_bounds__(256)
void tile_proj_kernel(const float* __restrict__ X, int C_in, int c0,
                      float* __restrict__ Fout, u32* __restrict__ Mout,
                      const float* __restrict__ Wk, float* __restrict__ out_part)
{
    constexpr int LPR = CC / 8;
    constexpr int RPB = 256 / LPR;
    __shared__ __align__(16) float tl[RPB][CC + 4];
    const int tid  = threadIdx.x;
    const int rloc = tid / LPR, j = tid % LPR;
    const int r    = blockIdx.x * RPB + rloc;
    if (r < MR) {
        const int n = r % NN;
        const float4 t0 = *(const float4*)&X[(size_t)n * C_in + c0 + 8 * j];
        const float4 t1 = *(const float4*)&X[(size_t)n * C_in + c0 + 8 * j + 4];
        ((float4*)Fout)[(size_t)r * (CC / 4) + 2 * j]     = t0;
        ((float4*)Fout)[(size_t)r * (CC / 4) + 2 * j + 1] = t1;
        uint4 m;
        m.x = pack2(t0.x, t0.y); m.y = pack2(t0.z, t0.w);
        m.z = pack2(t1.x, t1.y); m.w = pack2(t1.z, t1.w);
        ((uint4*)Mout)[(size_t)r * LPR + j] = m;
        *(float4*)&tl[rloc][8 * j]     = t0;
        *(float4*)&tl[rloc][8 * j + 4] = t1;
    }
    __syncthreads();
    project_rows<CC, FIRST>(tl, Wk, out_part, C_in, blockIdx.x * RPB);
}

template<int CC, bool CHEB>
__global__ __launch_bounds__(256)
void spmm_proj_kernel(const u32* __restrict__ Min, float* __restrict__ Fio,
                      u32* __restrict__ Mio,
                      const int* __restrict__ cols, const float* __restrict__ vals,
                      const float* __restrict__ Wk, float* __restrict__ out_part,
                      int C_in)
{
    constexpr int LPR = CC / 8;
    constexpr int RPB = 256 / LPR;
    __shared__ __align__(16) float tl[RPB][CC + 4];
    const int tid  = threadIdx.x;
    const int rloc = tid / LPR, j = tid % LPR;
    const int r    = blockIdx.x * RPB + rloc;
    if (r < MR) {
        const int nz = r * DEG;
        int   ci[DEG];
        float vv[DEG];
        const int4*   c4 = (const int4*)  (cols + nz);
        const float4* v4 = (const float4*)(vals + nz);
        #pragma unroll
        for (int q = 0; q < DEG / 4; ++q) {
            *(int4*)  &ci[4 * q] = c4[q];
            *(float4*)&vv[4 * q] = v4[q];
        }
        const uint4* M4 = (const uint4*)Min;
        float s[8] = {0.f, 0.f, 0.f, 0.f, 0.f, 0.f, 0.f, 0.f};
        #pragma unroll
        for (int d = 0; d < DEG; ++d) {
            const uint4 g = M4[(size_t)ci[d] * LPR + j];
            acc8(s, vv[d], g);
        }
        float t[8];
        if (CHEB) {
            const float4 p0 = ((const float4*)Fio)[(size_t)r * (CC / 4) + 2 * j];
            const float4 p1 = ((const float4*)Fio)[(size_t)r * (CC / 4) + 2 * j + 1];
            t[0] = 2.f * s[0] - p0.x; t[1] = 2.f * s[1] - p0.y;
            t[2] = 2.f * s[2] - p0.z; t[3] = 2.f * s[3] - p0.w;
            t[4] = 2.f * s[4] - p1.x; t[5] = 2.f * s[5] - p1.y;
            t[6] = 2.f * s[6] - p1.z; t[7] = 2.f * s[7] - p1.w;
        } else {
            #pragma unroll
            for (int i = 0; i < 8; ++i) t[i] = s[i];
        }
        ((float4*)Fio)[(size_t)r * (CC / 4) + 2 * j]     = make_float4(t[0], t[1], t[2], t[3]);
        ((float4*)Fio)[(size_t)r * (CC / 4) + 2 * j + 1] = make_float4(t[4], t[5], t[6], t[7]);
        uint4 m;
        m.x = pack2(t[0], t[1]); m.y = pack2(t[2], t[3]);
        m.z = pack2(t[4], t[5]); m.w = pack2(t[6], t[7]);
        ((uint4*)Mio)[(size_t)r * LPR + j] = m;
        *(float4*)&tl[rloc][8 * j]     = make_float4(t[0], t[1], t[2], t[3]);
        *(float4*)&tl[rloc][8 * j + 4] = make_float4(t[4], t[5], t[6], t[7]);
    }
    __syncthreads();
    project_rows<CC, false>(tl, Wk, out_part, C_in, blockIdx.x * RPB);
}

// ---------------- BN helpers ----------------
__global__ void bn_reduce_kernel(const float* __restrict__ part, float* __restrict__ acc)
{
    const int e = blockIdx.x * blockDim.x + threadIdx.x;
    if (e >= NN * 64) return;
    float s = 0.f;
    #pragma unroll
    for (int a = 0; a < NA; ++a) s += part[(size_t)a * NN * 64 + e];
    acc[e] = s;
}

__global__ __launch_bounds__(256)
void bn_stats_kernel(const float* __restrict__ acc, const float* __restrict__ gamma,
                     const float* __restrict__ beta, float* __restrict__ bnp)
{
    const int h = blockIdx.x;
    float s = 0.f, sq = 0.f;
    for (int n = threadIdx.x; n < NN; n += 256) {
        const float v = acc[(size_t)n * 64 + h];
        s += v; sq += v * v;
    }
    __shared__ float ls[256], lq[256];
    ls[threadIdx.x] = s; lq[threadIdx.x] = sq;
    __syncthreads();
    for (int st = 128; st > 0; st >>= 1) {
        if (threadIdx.x < st) { ls[threadIdx.x] += ls[threadIdx.x + st]; lq[threadIdx.x] += lq[threadIdx.x + st]; }
        __syncthreads();
    }
    if (threadIdx.x == 0) {
        const float mean = ls[0] / (float)NN;
        const float var  = lq[0] / (float)NN - mean * mean;
        const float sc   = gamma[h] / sqrtf(var + BN_EPS);
        bnp[h]      = sc;
        bnp[64 + h] = beta[h] - mean * sc;
    }
}

__global__ void bn_apply_kernel(const float* __restrict__ acc, const float* __restrict__ bnp,
                                float* __restrict__ H)
{
    const int e = blockIdx.x * blockDim.x + threadIdx.x;
    if (e >= NN * 64) return;
    const int h = e & 63;
    const float v = acc[e] * bnp[h] + bnp[64 + h];
    H[e] = v > 0.f ? v : 0.f;
}

// ---------------- fp32 GEMM (+bias, opt relu); 4+4 split (2-way LDS alias = free) -
template<bool RELU>
__global__ __launch_bounds__(256)
void gemm_bias_kernel(const float* __restrict__ A, const float* __restrict__ B,
                      const float* __restrict__ bias, float* __restrict__ C,
                      int Mm, int Nn, int Kk)
{
    __shared__ float As[16][132];
    __shared__ float Bs[16][132];
    const int tx = threadIdx.x & 15, ty = threadIdx.x >> 4;
    const int m0 = blockIdx.y * 128, n0 = blockIdx.x * 128;
    const bool full = (m0 + 128 <= Mm) && (n0 + 128 <= Nn);
    float acc[8][8] = {};
    for (int k0 = 0; k0 < Kk; k0 += 16) {
        if (full) {
            #pragma unroll
            for (int e = threadIdx.x; e < 512; e += 256) {
                const int i = e >> 2, q = e & 3;
                const float4 a4 = *(const float4*)&A[(size_t)(m0 + i) * Kk + k0 + 4 * q];
                As[4 * q + 0][i] = a4.x; As[4 * q + 1][i] = a4.y;
                As[4 * q + 2][i] = a4.z; As[4 * q + 3][i] = a4.w;
            }
            #pragma unroll
            for (int e = threadIdx.x; e < 512; e += 256) {
                const int kk = e >> 5, q = e & 31;
                *(float4*)&Bs[kk][4 * q] = *(const float4*)&B[(size_t)(k0 + kk) * Nn + n0 + 4 * q];
            }
        } else {
            for (int e = threadIdx.x; e < 128 * 16; e += 256) {
                const int i = e >> 4, kk = e & 15;
                const int row = m0 + i;
                As[kk][i] = (row < Mm) ? A[(size_t)row * Kk + k0 + kk] : 0.f;
            }
            for (int e = threadIdx.x; e < 16 * 128; e += 256) {
                const int kk = e >> 7, jj = e & 127;
                const int col = n0 + jj;
                Bs[kk][jj] = (col < Nn) ? B[(size_t)(k0 + kk) * Nn + col] : 0.f;
            }
        }
        __syncthreads();
        #pragma unroll
        for (int kk = 0; kk < 16; ++kk) {
            float av[8], bv[8];
            *(float4*)&av[0] = *(const float4*)&As[kk][ty * 4];
            *(float4*)&av[4] = *(const float4*)&As[kk][64 + ty * 4];
            *(float4*)&bv[0] = *(const float4*)&Bs[kk][tx * 4];
            *(float4*)&bv[4] = *(const float4*)&Bs[kk][64 + tx * 4];
            #pragma unroll
            for (int i = 0; i < 8; ++i)
                #pragma unroll
                for (int jj = 0; jj < 8; ++jj)
                    acc[i][jj] += av[i] * bv[jj];
        }
        __syncthreads();
    }
    if (full) {
        float4 bA = *(const float4*)&bias[n0 + tx * 4];
        float4 bB = *(const float4*)&bias[n0 + 64 + tx * 4];
        #pragma unroll
        for (int i = 0; i < 8; ++i) {
            const int row = m0 + (i < 4 ? ty * 4 + i : 64 + ty * 4 + (i - 4));
            float4 v0 = make_float4(acc[i][0] + bA.x, acc[i][1] + bA.y,
                                    acc[i][2] + bA.z, acc[i][3] + bA.w);
            float4 v1 = make_float4(acc[i][4] + bB.x, acc[i][5] + bB.y,
                                    acc[i][6] + bB.z, acc[i][7] + bB.w);
            if (RELU) {
                v0.x = fmaxf(v0.x, 0.f); v0.y = fmaxf(v0.y, 0.f);
                v0.z = fmaxf(v0.z, 0.f); v0.w = fmaxf(v0.w, 0.f);
                v1.x = fmaxf(v1.x, 0.f); v1.y = fmaxf(v1.y, 0.f);
                v1.z = fmaxf(v1.z, 0.f); v1.w = fmaxf(v1.w, 0.f);
            }
            *(float4*)&C[(size_t)row * Nn + n0 + tx * 4]      = v0;
            *(float4*)&C[(size_t)row * Nn + n0 + 64 + tx * 4] = v1;
        }
    } else {
        for (int i = 0; i < 8; ++i) {
            const int row = m0 + (i < 4 ? ty * 4 + i : 64 + ty * 4 + (i - 4));
            if (row >= Mm) continue;
            for (int jj = 0; jj < 8; ++jj) {
                const int col = n0 + (jj < 4 ? tx * 4 + jj : 64 + tx * 4 + (jj - 4));
                if (col >= Nn) continue;
                float v = acc[i][jj] + bias[col];
                if (RELU) v = fmaxf(v, 0.f);
                C[(size_t)row * Nn + col] = v;
            }
        }
    }
}

// ---------------- launchers ----------------
static bool launch_fused(bool cc64, bool first, const float* X, int C_in, int c0,
                         const int* cols, const float* vals, const float* W,
                         float* part, u32* Ma, u32* Mb, hipStream_t stream)
{
    const void* f;
    if (cc64) f = first ? (const void*)&conv_fused_kernel<64, true>
                        : (const void*)&conv_fused_kernel<64, false>;
    else      f = first ? (const void*)&conv_fused_kernel<32, true>
                        : (const void*)&conv_fused_kernel<32, false>;
    void* args[] = { (void*)&X, (void*)&C_in, (void*)&c0, (void*)&cols, (void*)&vals,
                     (void*)&W, (void*)&part, (void*)&Ma, (void*)&Mb };
    return hipLaunchCooperativeKernel(f, dim3(CBLK), dim3(256), args, 0, stream)
           == hipSuccess;
}

static void chunk_fallback(bool cc64, bool first, const float* X, int C_in, int c0,
                           const int* cols, const float* vals, const float* W0,
                           size_t wkstride, float* part, float* Fa, float* Fb,
                           u32* Ma, u32* Mb, hipStream_t stream)
{
    const int NB64 = (MR + 31) / 32;
    const int NB32 = (MR + 63) / 64;
    if (cc64) {
        if (first) tile_proj_kernel<64, true ><<<NB64, 256, 0, stream>>>(X, C_in, c0, Fa, Ma, W0, part);
        else       tile_proj_kernel<64, false><<<NB64, 256, 0, stream>>>(X, C_in, c0, Fa, Ma, W0, part);
        spmm_proj_kernel<64, false><<<NB64, 256, 0, stream>>>(Ma, Fb, Mb, cols, vals, W0 + wkstride, part, C_in);
        for (int k = 2; k < KC; ++k) {
            const u32* Min = (k & 1) ? Ma : Mb;
            float*     Fio = (k & 1) ? Fb : Fa;
            u32*       Mio = (k & 1) ? Mb : Ma;
            spmm_proj_kernel<64, true><<<NB64, 256, 0, stream>>>(Min, Fio, Mio, cols, vals,
                                                                 W0 + (size_t)k * wkstride, part, C_in);
        }
    } else {
        tile_proj_kernel<32, false><<<NB32, 256, 0, stream>>>(X, C_in, c0, Fa, Ma, W0, part);
        spmm_proj_kernel<32, false><<<NB32, 256, 0, stream>>>(Ma, Fb, Mb, cols, vals, W0 + wkstride, part, C_in);
        for (int k = 2; k < KC; ++k) {
            const u32* Min = (k & 1) ? Ma : Mb;
            float*     Fio = (k & 1) ? Fb : Fa;
            u32*       Mio = (k & 1) ? Mb : Ma;
            spmm_proj_kernel<32, true><<<NB32, 256, 0, stream>>>(Min, Fio, Mio, cols, vals,
                                                                 W0 + (size_t)k * wkstride, part, C_in);
        }
    }
}

extern "C" void kernel_launch(void* const* d_in, const int* in_sizes, int n_in,
                              void* d_out, int out_size, void* d_ws, size_t ws_size,
                              hipStream_t stream)
{
    (void)in_sizes; (void)n_in; (void)out_size; (void)ws_size;
    const float* x     = (const float*)d_in[0];
    const int*   cols  = (const int*)  d_in[2];
    const float* vals  = (const float*)d_in[3];
    const float* W1    = (const float*)d_in[4];
    const float* Wc    = (const float*)d_in[5];
    const float* gamma = (const float*)d_in[7];
    const float* beta  = (const float*)d_in[8];
    const float* fc2w  = (const float*)d_in[9];
    const float* fc2b  = (const float*)d_in[10];
    const float* fc3w  = (const float*)d_in[11];
    const float* fc3b  = (const float*)d_in[12];

    const size_t MT = (size_t)MR * 64;
    char* base = (char*)d_ws;
    size_t off = 0;
    float* Fa = (float*)(base + off); off += MT * 4;          // fallback fp32 state
    float* Fb = (float*)(base + off); off += MT * 4;
    u32* Ma   = (u32*)(base + off);   off += MT * 2;          // bf16 mirrors
    u32* Mb   = (u32*)(base + off);   off += MT * 2;
    float* part = (float*)(base + off); off += MT * 4;        // [8][NN][64]
    float* acc  = (float*)(base + off); off += (size_t)NN * 64 * 4;
    float* H    = (float*)(base + off); off += (size_t)NN * 64 * 4;
    float* f2   = (float*)(base + off); off += (size_t)NN * 256 * 4;
    float* bnp  = (float*)(base + off);

    // pre-flight: can the cooperative grid be co-resident?
    int dev = 0; hipGetDevice(&dev);
    int nCU = 0; hipDeviceGetAttribute(&nCU, hipDeviceAttributeMultiprocessorCount, dev);
    int mb64 = 0, mb32 = 0;
    hipOccupancyMaxActiveBlocksPerMultiprocessor(&mb64,
        (const void*)&conv_fused_kernel<64, false>, 256, 0);
    hipOccupancyMaxActiveBlocksPerMultiprocessor(&mb32,
        (const void*)&conv_fused_kernel<32, false>, 256, 0);
    bool coop = (nCU > 0) && (mb64 * nCU >= CBLK) && (mb32 * nCU >= CBLK);

    for (int li = 0; li < 6; ++li) {
        const int C_in = (li == 0) ? ND : 64;
        const float* X = (li == 0) ? x : H;
        const float* W = (li == 0) ? W1 : Wc + (size_t)(li - 1) * KC * (NA * 64) * 64;
        const size_t wk = (size_t)NA * C_in * 64;
        const int nfull = C_in / 64;
        for (int c = 0; c <= nfull; ++c) {
            const bool cc64 = (c < nfull);
            if (!cc64 && (C_in % 64) == 0) break;       // no tail chunk
            const int c0 = c * 64;
            const bool first = (c == 0);
            bool done = false;
            if (coop)
                done = launch_fused(cc64, first, X, C_in, c0, cols, vals, W, part, Ma, Mb, stream);
            if (!done) {
                coop = false;
                chunk_fallback(cc64, first, X, C_in, c0, cols, vals,
                               W + (size_t)c0 * 64, wk, part, Fa, Fb, Ma, Mb, stream);
            }
        }
        bn_reduce_kernel<<<(NN * 64 + 255) / 256, 256, 0, stream>>>(part, acc);
        bn_stats_kernel<<<64, 256, 0, stream>>>(acc, gamma + li * 64, beta + li * 64, bnp);
        bn_apply_kernel<<<(NN * 64 + 255) / 256, 256, 0, stream>>>(acc, bnp, H);
    }

    gemm_bias_kernel<true ><<<dim3(2, 54),  256, 0, stream>>>(H,  fc2w, fc2b, f2, NN, 256, 64);
    gemm_bias_kernel<false><<<dim3(54, 54), 256, 0, stream>>>(f2, fc3w, fc3b, (float*)d_out, NN, NN, 256);
}

// Round 6
// 5023.951 us; speedup vs baseline: 2.8633x; 1.1914x over previous
//
#include <hip/hip_runtime.h>
#include <cstdint>
#include <cstddef>

#define NN 6890
#define NA 8
#define KC 15
#define ND 544
#define MR (NA * NN)                 // 55120
#define DEG 16
#define BN_EPS 1e-5f
#define NSLOT 5                      // slab ring

typedef unsigned int u32;
typedef __attribute__((ext_vector_type(8))) short bf16x8;   // 8 bf16 (4 VGPR)
typedef __attribute__((ext_vector_type(4))) float f32x4;    // MFMA acc

__device__ __forceinline__ float blo(u32 u) { return __uint_as_float(u << 16); }
__device__ __forceinline__ float bhi(u32 u) { return __uint_as_float(u & 0xffff0000u); }
__device__ __forceinline__ u32 brnd(float f) {   // fp32 -> bf16 bits (RNE)
    u32 u = __float_as_uint(f);
    return (u + 0x7fffu + ((u >> 16) & 1u)) >> 16;
}
__device__ __forceinline__ u32 pack2(float a, float b) {
    return brnd(a) | (brnd(b) << 16);
}
__device__ __forceinline__ void acc8(float* s, float v, uint4 g) {
    s[0] += v * blo(g.x); s[1] += v * bhi(g.x);
    s[2] += v * blo(g.y); s[3] += v * bhi(g.y);
    s[4] += v * blo(g.z); s[5] += v * bhi(g.z);
    s[6] += v * blo(g.w); s[7] += v * bhi(g.w);
}
__device__ __forceinline__ bf16x8 as_bf8(uint4 u) {
    union { uint4 a; bf16x8 b; } c; c.a = u; return c.b;
}

// ---------------- k=0: T0 = X chunk -> F0 (fp32) + slab0 (bf16) ----------------
template<int CC>
__global__ __launch_bounds__(256)
void tile_slab_kernel(const float* __restrict__ X, int C_in, int c0,
                      float* __restrict__ F0, u32* __restrict__ slab0)
{
    constexpr int LPR = CC / 8;
    constexpr int RPB = 256 / LPR;
    const int tid = threadIdx.x;
    const int j = tid % LPR, rloc = tid / LPR;
    const int r = blockIdx.x * RPB + rloc;
    if (r >= MR) return;
    const int n = r % NN;
    const float4 t0 = *(const float4*)&X[(size_t)n * C_in + c0 + 8 * j];
    const float4 t1 = *(const float4*)&X[(size_t)n * C_in + c0 + 8 * j + 4];
    ((float4*)F0)[(size_t)r * (CC / 4) + 2 * j]     = t0;
    ((float4*)F0)[(size_t)r * (CC / 4) + 2 * j + 1] = t1;
    uint4 m;
    m.x = pack2(t0.x, t0.y); m.y = pack2(t0.z, t0.w);
    m.z = pack2(t1.x, t1.y); m.w = pack2(t1.z, t1.w);
    ((uint4*)slab0)[(size_t)r * LPR + j] = m;
}

// ---------------- recurrence step: gather slab_prev, write F + slab_cur ---------
// CHEB: t = 2*L*T_{k-1} - T_{k-2} (T_{k-2} fp32 in F, in-place); else t = L*T_{k-1}
template<int CC, bool CHEB>
__global__ __launch_bounds__(256)
void spmm_slab_kernel(const u32* __restrict__ sprev, u32* __restrict__ scur,
                      float* __restrict__ F,
                      const int* __restrict__ cols, const float* __restrict__ vals)
{
    constexpr int LPR = CC / 8;
    constexpr int RPB = 256 / LPR;
    const int tid = threadIdx.x;
    const int j = tid % LPR, rloc = tid / LPR;
    const int r = blockIdx.x * RPB + rloc;
    if (r >= MR) return;

    const int nz = r * DEG;
    int   ci[DEG];
    float vv[DEG];
    const int4*   c4 = (const int4*)  (cols + nz);
    const float4* v4 = (const float4*)(vals + nz);
    #pragma unroll
    for (int q = 0; q < DEG / 4; ++q) {
        *(int4*)  &ci[4 * q] = c4[q];
        *(float4*)&vv[4 * q] = v4[q];
    }
    const uint4* S4 = (const uint4*)sprev;
    float s[8] = {0.f, 0.f, 0.f, 0.f, 0.f, 0.f, 0.f, 0.f};
    #pragma unroll
    for (int d = 0; d < DEG; ++d) {
        const uint4 g = S4[(size_t)ci[d] * LPR + j];
        acc8(s, vv[d], g);
    }
    float t[8];
    if (CHEB) {
        const float4 p0 = ((const float4*)F)[(size_t)r * (CC / 4) + 2 * j];
        const float4 p1 = ((const float4*)F)[(size_t)r * (CC / 4) + 2 * j + 1];
        t[0] = 2.f * s[0] - p0.x; t[1] = 2.f * s[1] - p0.y;
        t[2] = 2.f * s[2] - p0.z; t[3] = 2.f * s[3] - p0.w;
        t[4] = 2.f * s[4] - p1.x; t[5] = 2.f * s[5] - p1.y;
        t[6] = 2.f * s[6] - p1.z; t[7] = 2.f * s[7] - p1.w;
    } else {
        #pragma unroll
        for (int i = 0; i < 8; ++i) t[i] = s[i];
    }
    ((float4*)F)[(size_t)r * (CC / 4) + 2 * j]     = make_float4(t[0], t[1], t[2], t[3]);
    ((float4*)F)[(size_t)r * (CC / 4) + 2 * j + 1] = make_float4(t[4], t[5], t[6], t[7]);
    uint4 m;
    m.x = pack2(t[0], t[1]); m.y = pack2(t[2], t[3]);
    m.z = pack2(t[4], t[5]); m.w = pack2(t[6], t[7]);
    ((uint4*)scur)[(size_t)r * LPR + j] = m;
}

// ---------------- MFMA projection over a 5-slab group ---------------------------
// part[a][n][h] (+)= sum_{kk} T_{kbase+kk}[a*NN+n][cc] * W[kbase+kk][a*C_in+c0+cc][h]
// A = bf16 slab rows (16B/lane direct load). B = W staged in LDS as bf16 hi+lo
// (weight precision preserved: W ~= hi + lo). MFMA 16x16x32_bf16:
//   A-frag: row=l&15, k=(l>>4)*8+i ; B-frag: col=l&15, k=(l>>4)*8+i ;
//   C/D: col=l&15, row=(l>>4)*4+reg   [doc §3, m89-verified]
template<int CCH, bool FIRST>          // CCH = CC/32
__global__ __launch_bounds__(256)
void proj_mfma_kernel(const uint4* __restrict__ slabs4, const float* __restrict__ W,
                      float* __restrict__ part, int C_in, int c0, int kbase)
{
    constexpr int CC  = CCH * 32;
    constexpr int LPR = CC / 8;        // uint4 per row
    __shared__ u32 WH[CCH * 1024];
    __shared__ u32 WL[CCH * 1024];

    const int tid = threadIdx.x;
    const int l = tid & 63, w = tid >> 6;
    const int a = blockIdx.y;
    const int rows0 = blockIdx.x * 64;
    const int hi16 = l >> 4;           // 0..3
    const size_t wk = (size_t)NA * C_in * 64;
    const float* Wb = W + ((size_t)a * C_in + c0) * 64;

    const int arow = rows0 + w * 16 + (l & 15);
    const int arc  = arow < NN ? arow : NN - 1;
    const size_t abase = (size_t)(a * NN + arc) * LPR;

    f32x4 acc[4];
    #pragma unroll
    for (int nt = 0; nt < 4; ++nt) {
        #pragma unroll
        for (int rr = 0; rr < 4; ++rr) {
            const int orow = rows0 + w * 16 + hi16 * 4 + rr;
            float v = 0.f;
            if (!FIRST && orow < NN)
                v = part[((size_t)a * NN + orow) * 64 + nt * 16 + (l & 15)];
            acc[nt][rr] = v;
        }
    }

    for (int kk = 0; kk < 5; ++kk) {
        const int k = kbase + kk;
        const int slot = k % NSLOT;
        const float* Wk = Wb + (size_t)k * wk;
        __syncthreads();
        for (int e = tid; e < CCH * 1024; e += 256) {
            const int i2 = e & 3;
            const int ll = (e >> 2) & 63;
            const int nt = (e >> 8) & 3;
            const int h  = e >> 10;
            const int cc  = h * 32 + (ll >> 4) * 8 + 2 * i2;
            const int col = nt * 16 + (ll & 15);
            const float w0 = Wk[(size_t)cc * 64 + col];
            const float w1 = Wk[(size_t)(cc + 1) * 64 + col];
            const u32 h0 = brnd(w0), h1 = brnd(w1);
            WH[e] = h0 | (h1 << 16);
            WL[e] = pack2(w0 - blo(h0), w1 - blo(h1));
        }
        __syncthreads();

        const uint4* S4 = slabs4 + (size_t)slot * MR * LPR;
        #pragma unroll
        for (int h = 0; h < CCH; ++h) {
            const bf16x8 af = as_bf8(S4[abase + h * 4 + hi16]);
            #pragma unroll
            for (int nt = 0; nt < 4; ++nt) {
                const int be = ((h * 4 + nt) * 64 + l) * 4;
                const bf16x8 bh = as_bf8(*(const uint4*)&WH[be]);
                const bf16x8 bl = as_bf8(*(const uint4*)&WL[be]);
                acc[nt] = __builtin_amdgcn_mfma_f32_16x16x32_bf16(af, bh, acc[nt], 0, 0, 0);
                acc[nt] = __builtin_amdgcn_mfma_f32_16x16x32_bf16(af, bl, acc[nt], 0, 0, 0);
            }
        }
    }

    #pragma unroll
    for (int nt = 0; nt < 4; ++nt) {
        #pragma unroll
        for (int rr = 0; rr < 4; ++rr) {
            const int orow = rows0 + w * 16 + hi16 * 4 + rr;
            if (orow < NN)
                part[((size_t)a * NN + orow) * 64 + nt * 16 + (l & 15)] = acc[nt][rr];
        }
    }
}

// ---------------- BN helpers ----------------
__global__ void bn_reduce_kernel(const float* __restrict__ part, float* __restrict__ acc)
{
    const int e = blockIdx.x * blockDim.x + threadIdx.x;
    if (e >= NN * 64) return;
    float s = 0.f;
    #pragma unroll
    for (int a = 0; a < NA; ++a) s += part[(size_t)a * NN * 64 + e];
    acc[e] = s;
}

__global__ __launch_bounds__(256)
void bn_stats_kernel(const float* __restrict__ acc, const float* __restrict__ gamma,
                     const float* __restrict__ beta, float* __restrict__ bnp)
{
    const int h = blockIdx.x;
    float s = 0.f, sq = 0.f;
    for (int n = threadIdx.x; n < NN; n += 256) {
        const float v = acc[(size_t)n * 64 + h];
        s += v; sq += v * v;
    }
    __shared__ float ls[256], lq[256];
    ls[threadIdx.x] = s; lq[threadIdx.x] = sq;
    __syncthreads();
    for (int st = 128; st > 0; st >>= 1) {
        if (threadIdx.x < st) { ls[threadIdx.x] += ls[threadIdx.x + st]; lq[threadIdx.x] += lq[threadIdx.x + st]; }
        __syncthreads();
    }
    if (threadIdx.x == 0) {
        const float mean = ls[0] / (float)NN;
        const float var  = lq[0] / (float)NN - mean * mean;
        const float sc   = gamma[h] / sqrtf(var + BN_EPS);
        bnp[h]      = sc;
        bnp[64 + h] = beta[h] - mean * sc;
    }
}

__global__ void bn_apply_kernel(const float* __restrict__ acc, const float* __restrict__ bnp,
                                float* __restrict__ H)
{
    const int e = blockIdx.x * blockDim.x + threadIdx.x;
    if (e >= NN * 64) return;
    const int h = e & 63;
    const float v = acc[e] * bnp[h] + bnp[64 + h];
    H[e] = v > 0.f ? v : 0.f;
}

// ---------------- fp32 GEMM (+bias, opt relu); 4+4 split (2-way LDS alias = free) -
template<bool RELU>
__global__ __launch_bounds__(256)
void gemm_bias_kernel(const float* __restrict__ A, const float* __restrict__ B,
                      const float* __restrict__ bias, float* __restrict__ C,
                      int Mm, int Nn, int Kk)
{
    __shared__ float As[16][132];
    __shared__ float Bs[16][132];
    const int tx = threadIdx.x & 15, ty = threadIdx.x >> 4;
    const int m0 = blockIdx.y * 128, n0 = blockIdx.x * 128;
    const bool full = (m0 + 128 <= Mm) && (n0 + 128 <= Nn);
    float acc[8][8] = {};
    for (int k0 = 0; k0 < Kk; k0 += 16) {
        if (full) {
            #pragma unroll
            for (int e = threadIdx.x; e < 512; e += 256) {
                const int i = e >> 2, q = e & 3;
                const float4 a4 = *(const float4*)&A[(size_t)(m0 + i) * Kk + k0 + 4 * q];
                As[4 * q + 0][i] = a4.x; As[4 * q + 1][i] = a4.y;
                As[4 * q + 2][i] = a4.z; As[4 * q + 3][i] = a4.w;
            }
            #pragma unroll
            for (int e = threadIdx.x; e < 512; e += 256) {
                const int kk = e >> 5, q = e & 31;
                *(float4*)&Bs[kk][4 * q] = *(const float4*)&B[(size_t)(k0 + kk) * Nn + n0 + 4 * q];
            }
        } else {
            for (int e = threadIdx.x; e < 128 * 16; e += 256) {
                const int i = e >> 4, kk = e & 15;
                const int row = m0 + i;
                As[kk][i] = (row < Mm) ? A[(size_t)row * Kk + k0 + kk] : 0.f;
            }
            for (int e = threadIdx.x; e < 16 * 128; e += 256) {
                const int kk = e >> 7, jj = e & 127;
                const int col = n0 + jj;
                Bs[kk][jj] = (col < Nn) ? B[(size_t)(k0 + kk) * Nn + col] : 0.f;
            }
        }
        __syncthreads();
        #pragma unroll
        for (int kk = 0; kk < 16; ++kk) {
            float av[8], bv[8];
            *(float4*)&av[0] = *(const float4*)&As[kk][ty * 4];
            *(float4*)&av[4] = *(const float4*)&As[kk][64 + ty * 4];
            *(float4*)&bv[0] = *(const float4*)&Bs[kk][tx * 4];
            *(float4*)&bv[4] = *(const float4*)&Bs[kk][64 + tx * 4];
            #pragma unroll
            for (int i = 0; i < 8; ++i)
                #pragma unroll
                for (int jj = 0; jj < 8; ++jj)
                    acc[i][jj] += av[i] * bv[jj];
        }
        __syncthreads();
    }
    if (full) {
        float4 bA = *(const float4*)&bias[n0 + tx * 4];
        float4 bB = *(const float4*)&bias[n0 + 64 + tx * 4];
        #pragma unroll
        for (int i = 0; i < 8; ++i) {
            const int row = m0 + (i < 4 ? ty * 4 + i : 64 + ty * 4 + (i - 4));
            float4 v0 = make_float4(acc[i][0] + bA.x, acc[i][1] + bA.y,
                                    acc[i][2] + bA.z, acc[i][3] + bA.w);
            float4 v1 = make_float4(acc[i][4] + bB.x, acc[i][5] + bB.y,
                                    acc[i][6] + bB.z, acc[i][7] + bB.w);
            if (RELU) {
                v0.x = fmaxf(v0.x, 0.f); v0.y = fmaxf(v0.y, 0.f);
                v0.z = fmaxf(v0.z, 0.f); v0.w = fmaxf(v0.w, 0.f);
                v1.x = fmaxf(v1.x, 0.f); v1.y = fmaxf(v1.y, 0.f);
                v1.z = fmaxf(v1.z, 0.f); v1.w = fmaxf(v1.w, 0.f);
            }
            *(float4*)&C[(size_t)row * Nn + n0 + tx * 4]      = v0;
            *(float4*)&C[(size_t)row * Nn + n0 + 64 + tx * 4] = v1;
        }
    } else {
        for (int i = 0; i < 8; ++i) {
            const int row = m0 + (i < 4 ? ty * 4 + i : 64 + ty * 4 + (i - 4));
            if (row >= Mm) continue;
            for (int jj = 0; jj < 8; ++jj) {
                const int col = n0 + (jj < 4 ? tx * 4 + jj : 64 + tx * 4 + (jj - 4));
                if (col >= Nn) continue;
                float v = acc[i][jj] + bias[col];
                if (RELU) v = fmaxf(v, 0.f);
                C[(size_t)row * Nn + col] = v;
            }
        }
    }
}

// ---------------- chunk driver ----------------
template<int CC>
static void run_chunk(bool chunkFirst, const float* X, int C_in, int c0,
                      const int* cols, const float* vals, const float* W,
                      uint4* slabs4, float* F0, float* F1, float* part,
                      hipStream_t stream)
{
    constexpr int LPR = CC / 8;
    constexpr int RPB = 256 / LPR;
    const int NB = (MR + RPB - 1) / RPB;
    const size_t sstride = (size_t)MR * LPR;
    constexpr int CCH = CC / 32;

    tile_slab_kernel<CC><<<NB, 256, 0, stream>>>(X, C_in, c0, F0, (u32*)slabs4);
    spmm_slab_kernel<CC, false><<<NB, 256, 0, stream>>>(
        (const u32*)slabs4, (u32*)(slabs4 + sstride), F1, cols, vals);
    for (int k = 2; k < KC; ++k) {
        const u32* sp = (const u32*)(slabs4 + (size_t)((k - 1) % NSLOT) * sstride);
        u32*       sc = (u32*)(slabs4 + (size_t)(k % NSLOT) * sstride);
        float*     F  = (k & 1) ? F1 : F0;
        spmm_slab_kernel<CC, true><<<NB, 256, 0, stream>>>(sp, sc, F, cols, vals);
        if (k == 4) {
            if (chunkFirst)
                proj_mfma_kernel<CCH, true ><<<dim3(108, 8), 256, 0, stream>>>(slabs4, W, part, C_in, c0, 0);
            else
                proj_mfma_kernel<CCH, false><<<dim3(108, 8), 256, 0, stream>>>(slabs4, W, part, C_in, c0, 0);
        } else if (k == 9) {
            proj_mfma_kernel<CCH, false><<<dim3(108, 8), 256, 0, stream>>>(slabs4, W, part, C_in, c0, 5);
        }
    }
    proj_mfma_kernel<CCH, false><<<dim3(108, 8), 256, 0, stream>>>(slabs4, W, part, C_in, c0, 10);
}

extern "C" void kernel_launch(void* const* d_in, const int* in_sizes, int n_in,
                              void* d_out, int out_size, void* d_ws, size_t ws_size,
                              hipStream_t stream)
{
    (void)in_sizes; (void)n_in; (void)out_size; (void)ws_size;
    const float* x     = (const float*)d_in[0];
    const int*   cols  = (const int*)  d_in[2];
    const float* vals  = (const float*)d_in[3];
    const float* W1    = (const float*)d_in[4];
    const float* Wc    = (const float*)d_in[5];
    const float* gamma = (const float*)d_in[7];
    const float* beta  = (const float*)d_in[8];
    const float* fc2w  = (const float*)d_in[9];
    const float* fc2b  = (const float*)d_in[10];
    const float* fc3w  = (const float*)d_in[11];
    const float* fc3b  = (const float*)d_in[12];

    const size_t MT = (size_t)MR * 64;
    char* base = (char*)d_ws;
    size_t off = 0;
    uint4* slabs4 = (uint4*)(base + off); off += (size_t)NSLOT * MT * 2;  // 35.3 MB (5 bf16 slabs)
    float* F0   = (float*)(base + off); off += MT * 4;                    // 14.1 MB
    float* F1   = (float*)(base + off); off += MT * 4;                    // 14.1 MB
    float* part = (float*)(base + off); off += MT * 4;                    // 14.1 MB
    float* H    = (float*)(base + off); off += (size_t)NN * 64 * 4;       // 1.8 MB
    float* bnp  = (float*)(base + off); off += 1024;
    // live only between conv phases / after convs -> overlap onto slab region
    float* acc  = (float*)slabs4;                                          // 1.8 MB
    float* f2   = (float*)((char*)slabs4 + (size_t)4 * 1024 * 1024);       // 7.1 MB

    for (int li = 0; li < 6; ++li) {
        const int C_in = (li == 0) ? ND : 64;
        const float* X = (li == 0) ? x : H;
        const float* W = (li == 0) ? W1 : Wc + (size_t)(li - 1) * KC * (NA * 64) * 64;
        const int nfull = C_in / 64;
        for (int c = 0; c < nfull; ++c)
            run_chunk<64>(c == 0, X, C_in, c * 64, cols, vals, W, slabs4, F0, F1, part, stream);
        if (C_in % 64)
            run_chunk<32>(false, X, C_in, nfull * 64, cols, vals, W, slabs4, F0, F1, part, stream);

        bn_reduce_kernel<<<(NN * 64 + 255) / 256, 256, 0, stream>>>(part, acc);
        bn_stats_kernel<<<64, 256, 0, stream>>>(acc, gamma + li * 64, beta + li * 64, bnp);
        bn_apply_kernel<<<(NN * 64 + 255) / 256, 256, 0, stream>>>(acc, bnp, H);
    }

    gemm_bias_kernel<true ><<<dim3(2, 54),  256, 0, stream>>>(H,  fc2w, fc2b, f2, NN, 256, 64);
    gemm_bias_kernel<false><<<dim3(54, 54), 256, 0, stream>>>(f2, fc3w, fc3b, (float*)d_out, NN, NN, 256);
}

// Round 7
// 4495.274 us; speedup vs baseline: 3.2000x; 1.1176x over previous
//
#include <hip/hip_runtime.h>
#include <cstdint>
#include <cstddef>

#define NN 6890
#define NA 8
#define KC 15
#define ND 544
#define MR (NA * NN)                 // 55120
#define DEG 16
#define BN_EPS 1e-5f
#define PB 864                       // proj blocks: 108 row-groups x 8 angles
#define NRG 108

typedef unsigned int u32;
typedef _Float16 f16;
typedef __attribute__((ext_vector_type(8))) _Float16 f16x8;
typedef __attribute__((ext_vector_type(4))) float f32x4;

union U4H8 { uint4 q; f16 h[8]; f16x8 v; };

__device__ __forceinline__ u32 packh(float a, float b) {
    union { f16 h[2]; u32 u; } c;
    c.h[0] = (f16)a; c.h[1] = (f16)b; return c.u;
}
__device__ __forceinline__ uint4 pack8h(const float* t) {
    uint4 m;
    m.x = packh(t[0], t[1]); m.y = packh(t[2], t[3]);
    m.z = packh(t[4], t[5]); m.w = packh(t[6], t[7]);
    return m;
}
__device__ __forceinline__ void acc8h(float* s, float v, uint4 g) {
    U4H8 c; c.q = g;
    #pragma unroll
    for (int i = 0; i < 8; ++i) s[i] += v * (float)c.h[i];
}

// ---------------- k=0: T0 = X chunk -> fp16 slab slot 0 ----------------
template<int CC>
__global__ __launch_bounds__(256)
void tile_slab_kernel(const float* __restrict__ X, int C_in, int c0,
                      uint4* __restrict__ slab0)
{
    constexpr int LPR = CC / 8;
    constexpr int RPB = 256 / LPR;
    const int tid = threadIdx.x;
    const int j = tid % LPR, rloc = tid / LPR;
    const int r = blockIdx.x * RPB + rloc;
    if (r >= MR) return;
    const int n = r % NN;
    const float4 t0 = *(const float4*)&X[(size_t)n * C_in + c0 + 8 * j];
    const float4 t1 = *(const float4*)&X[(size_t)n * C_in + c0 + 8 * j + 4];
    float t[8] = { t0.x, t0.y, t0.z, t0.w, t1.x, t1.y, t1.z, t1.w };
    slab0[(size_t)r * LPR + j] = pack8h(t);
}

// ---------------- spmm body: gather slab(k-1), carry slab(k-2), write slab(k) ----
template<int CC, bool CHEB>
__device__ __forceinline__
void spmm_body(const uint4* __restrict__ sprev, const uint4* __restrict__ scarry,
               uint4* __restrict__ scur,
               const int* __restrict__ cols, const float* __restrict__ vals)
{
    constexpr int LPR = CC / 8;
    constexpr int RPB = 256 / LPR;
    const int tid = threadIdx.x;
    const int j = tid % LPR, rloc = tid / LPR;
    const int r = blockIdx.x * RPB + rloc;
    if (r >= MR) return;

    const int nz = r * DEG;
    int   ci[DEG];
    float vv[DEG];
    const int4*   c4 = (const int4*)  (cols + nz);
    const float4* v4 = (const float4*)(vals + nz);
    #pragma unroll
    for (int q = 0; q < DEG / 4; ++q) {
        *(int4*)  &ci[4 * q] = c4[q];
        *(float4*)&vv[4 * q] = v4[q];
    }
    float s[8] = {0.f, 0.f, 0.f, 0.f, 0.f, 0.f, 0.f, 0.f};
    #pragma unroll
    for (int d = 0; d < DEG; ++d) {
        const uint4 g = sprev[(size_t)ci[d] * LPR + j];
        acc8h(s, vv[d], g);
    }
    float t[8];
    if (CHEB) {
        U4H8 p; p.q = scarry[(size_t)r * LPR + j];
        #pragma unroll
        for (int i = 0; i < 8; ++i) t[i] = 2.f * s[i] - (float)p.h[i];
    } else {
        #pragma unroll
        for (int i = 0; i < 8; ++i) t[i] = s[i];
    }
    scur[(size_t)r * LPR + j] = pack8h(t);
}

// ---------------- proj body: part[a][n][h] (+)= T_k[a*NN+n][cc] * W_k[a*C+cc][h] --
// A = fp16 slab rows (16B/lane). B = W as fp16 hi+lo in LDS (fp32-grade weights).
// mfma_f32_16x16x32_f16: A row=l&15,k=(l>>4)*8+i; B col=l&15,k likewise;
// C/D col=l&15, row=(l>>4)*4+reg  [m89-verified layout, dtype-independent]
template<int CC, bool FIRSTP>
__device__ __forceinline__
void proj_body(int pb, const uint4* __restrict__ sl, const float* __restrict__ W,
               float* __restrict__ part, int C_in, int c0, int kproj,
               u32* WH, u32* WL)
{
    constexpr int CCH = CC / 32;
    constexpr int LPR = CC / 8;
    const int tid = threadIdx.x;
    const int l = tid & 63, w = tid >> 6;
    const int a = pb / NRG, rg = pb % NRG;
    const int rows0 = rg * 64;
    const int hi16 = l >> 4;
    const float* Wk = W + ((size_t)kproj * NA * C_in + (size_t)a * C_in + c0) * 64;

    for (int e = tid; e < CCH * 1024; e += 256) {
        const int i2 = e & 3;
        const int ll = (e >> 2) & 63;
        const int nt = (e >> 8) & 3;
        const int h  = e >> 10;
        const int cc  = h * 32 + (ll >> 4) * 8 + 2 * i2;
        const int col = nt * 16 + (ll & 15);
        const float w0 = Wk[(size_t)cc * 64 + col];
        const float w1 = Wk[(size_t)(cc + 1) * 64 + col];
        const f16 h0 = (f16)w0, h1 = (f16)w1;
        union { f16 h[2]; u32 u; } ph, pl;
        ph.h[0] = h0; ph.h[1] = h1;
        pl.h[0] = (f16)(w0 - (float)h0); pl.h[1] = (f16)(w1 - (float)h1);
        WH[e] = ph.u; WL[e] = pl.u;
    }
    __syncthreads();

    const int arow = rows0 + w * 16 + (l & 15);
    const int arc  = arow < NN ? arow : NN - 1;
    const size_t abase = (size_t)(a * NN + arc) * LPR;

    f32x4 acc[4];
    #pragma unroll
    for (int nt = 0; nt < 4; ++nt) {
        #pragma unroll
        for (int rr = 0; rr < 4; ++rr) {
            const int orow = rows0 + w * 16 + hi16 * 4 + rr;
            float v = 0.f;
            if (!FIRSTP && orow < NN)
                v = part[((size_t)a * NN + orow) * 64 + nt * 16 + (l & 15)];
            acc[nt][rr] = v;
        }
    }
    #pragma unroll
    for (int h = 0; h < CCH; ++h) {
        U4H8 af; af.q = sl[abase + h * 4 + hi16];
        #pragma unroll
        for (int nt = 0; nt < 4; ++nt) {
            const int be = ((h * 4 + nt) * 64 + l) * 4;
            U4H8 bh, bl;
            bh.q = *(const uint4*)&WH[be];
            bl.q = *(const uint4*)&WL[be];
            acc[nt] = __builtin_amdgcn_mfma_f32_16x16x32_f16(af.v, bh.v, acc[nt], 0, 0, 0);
            acc[nt] = __builtin_amdgcn_mfma_f32_16x16x32_f16(af.v, bl.v, acc[nt], 0, 0, 0);
        }
    }
    #pragma unroll
    for (int nt = 0; nt < 4; ++nt) {
        #pragma unroll
        for (int rr = 0; rr < 4; ++rr) {
            const int orow = rows0 + w * 16 + hi16 * 4 + rr;
            if (orow < NN)
                part[((size_t)a * NN + orow) * 64 + nt * 16 + (l & 15)] = acc[nt][rr];
        }
    }
}

// ---------------- combined dispatch: spmm(k) blocks + proj(k-1) blocks ----------
template<int CC, bool CHEB, bool FIRSTP>
__global__ __launch_bounds__(256)
void step_kernel(const uint4* __restrict__ sprev, const uint4* __restrict__ scarry,
                 uint4* __restrict__ scur,
                 const int* __restrict__ cols, const float* __restrict__ vals,
                 const float* __restrict__ W, float* __restrict__ part,
                 int C_in, int c0, int kproj, int NB)
{
    constexpr int CCH = CC / 32;
    __shared__ u32 WH[CCH * 1024];
    __shared__ u32 WL[CCH * 1024];
    if ((int)blockIdx.x < NB) {
        spmm_body<CC, CHEB>(sprev, scarry, scur, cols, vals);
    } else {
        proj_body<CC, FIRSTP>((int)blockIdx.x - NB, sprev, W, part, C_in, c0, kproj, WH, WL);
    }
}

template<int CC>
__global__ __launch_bounds__(256)
void proj_only_kernel(const uint4* __restrict__ sl, const float* __restrict__ W,
                      float* __restrict__ part, int C_in, int c0, int kproj)
{
    constexpr int CCH = CC / 32;
    __shared__ u32 WH[CCH * 1024];
    __shared__ u32 WL[CCH * 1024];
    proj_body<CC, false>((int)blockIdx.x, sl, W, part, C_in, c0, kproj, WH, WL);
}

// ---------------- BN helpers ----------------
__global__ void bn_reduce_kernel(const float* __restrict__ part, float* __restrict__ acc)
{
    const int e = blockIdx.x * blockDim.x + threadIdx.x;
    if (e >= NN * 64) return;
    float s = 0.f;
    #pragma unroll
    for (int a = 0; a < NA; ++a) s += part[(size_t)a * NN * 64 + e];
    acc[e] = s;
}

__global__ __launch_bounds__(256)
void bn_stats_kernel(const float* __restrict__ acc, const float* __restrict__ gamma,
                     const float* __restrict__ beta, float* __restrict__ bnp)
{
    const int h = blockIdx.x;
    float s = 0.f, sq = 0.f;
    for (int n = threadIdx.x; n < NN; n += 256) {
        const float v = acc[(size_t)n * 64 + h];
        s += v; sq += v * v;
    }
    __shared__ float ls[256], lq[256];
    ls[threadIdx.x] = s; lq[threadIdx.x] = sq;
    __syncthreads();
    for (int st = 128; st > 0; st >>= 1) {
        if (threadIdx.x < st) { ls[threadIdx.x] += ls[threadIdx.x + st]; lq[threadIdx.x] += lq[threadIdx.x + st]; }
        __syncthreads();
    }
    if (threadIdx.x == 0) {
        const float mean = ls[0] / (float)NN;
        const float var  = lq[0] / (float)NN - mean * mean;
        const float sc   = gamma[h] / sqrtf(var + BN_EPS);
        bnp[h]      = sc;
        bnp[64 + h] = beta[h] - mean * sc;
    }
}

__global__ void bn_apply_kernel(const float* __restrict__ acc, const float* __restrict__ bnp,
                                float* __restrict__ H)
{
    const int e = blockIdx.x * blockDim.x + threadIdx.x;
    if (e >= NN * 64) return;
    const int h = e & 63;
    const float v = acc[e] * bnp[h] + bnp[64 + h];
    H[e] = v > 0.f ? v : 0.f;
}

// ---------------- fc2: fp32 GEMM (+bias, relu), 4+4 split tiles ----------------
template<bool RELU>
__global__ __launch_bounds__(256)
void gemm_bias_kernel(const float* __restrict__ A, const float* __restrict__ B,
                      const float* __restrict__ bias, float* __restrict__ C,
                      int Mm, int Nn, int Kk)
{
    __shared__ float As[16][132];
    __shared__ float Bs[16][132];
    const int tx = threadIdx.x & 15, ty = threadIdx.x >> 4;
    const int m0 = blockIdx.y * 128, n0 = blockIdx.x * 128;
    const bool full = (m0 + 128 <= Mm) && (n0 + 128 <= Nn);
    float acc[8][8] = {};
    for (int k0 = 0; k0 < Kk; k0 += 16) {
        if (full) {
            #pragma unroll
            for (int e = threadIdx.x; e < 512; e += 256) {
                const int i = e >> 2, q = e & 3;
                const float4 a4 = *(const float4*)&A[(size_t)(m0 + i) * Kk + k0 + 4 * q];
                As[4 * q + 0][i] = a4.x; As[4 * q + 1][i] = a4.y;
                As[4 * q + 2][i] = a4.z; As[4 * q + 3][i] = a4.w;
            }
            #pragma unroll
            for (int e = threadIdx.x; e < 512; e += 256) {
                const int kk = e >> 5, q = e & 31;
                *(float4*)&Bs[kk][4 * q] = *(const float4*)&B[(size_t)(k0 + kk) * Nn + n0 + 4 * q];
            }
        } else {
            for (int e = threadIdx.x; e < 128 * 16; e += 256) {
                const int i = e >> 4, kk = e & 15;
                const int row = m0 + i;
                As[kk][i] = (row < Mm) ? A[(size_t)row * Kk + k0 + kk] : 0.f;
            }
            for (int e = threadIdx.x; e < 16 * 128; e += 256) {
                const int kk = e >> 7, jj = e & 127;
                const int col = n0 + jj;
                Bs[kk][jj] = (col < Nn) ? B[(size_t)(k0 + kk) * Nn + col] : 0.f;
            }
        }
        __syncthreads();
        #pragma unroll
        for (int kk = 0; kk < 16; ++kk) {
            float av[8], bv[8];
            *(float4*)&av[0] = *(const float4*)&As[kk][ty * 4];
            *(float4*)&av[4] = *(const float4*)&As[kk][64 + ty * 4];
            *(float4*)&bv[0] = *(const float4*)&Bs[kk][tx * 4];
            *(float4*)&bv[4] = *(const float4*)&Bs[kk][64 + tx * 4];
            #pragma unroll
            for (int i = 0; i < 8; ++i)
                #pragma unroll
                for (int jj = 0; jj < 8; ++jj)
                    acc[i][jj] += av[i] * bv[jj];
        }
        __syncthreads();
    }
    for (int i = 0; i < 8; ++i) {
        const int row = m0 + (i < 4 ? ty * 4 + i : 64 + ty * 4 + (i - 4));
        if (row >= Mm) continue;
        for (int jj = 0; jj < 8; ++jj) {
            const int col = n0 + (jj < 4 ? tx * 4 + jj : 64 + tx * 4 + (jj - 4));
            if (col >= Nn) continue;
            float v = acc[i][jj] + bias[col];
            if (RELU) v = fmaxf(v, 0.f);
            C[(size_t)row * Nn + col] = v;
        }
    }
}

// ---------------- fc3: fp16-split MFMA GEMM (hi+lo, 3 products) ----------------
__global__ __launch_bounds__(256)
void fc3_mfma_kernel(const float* __restrict__ A, const float* __restrict__ Bm,
                     const float* __restrict__ bias, float* __restrict__ C)
{
    constexpr int Mm = NN, Nn = NN, Kk = 256;
    __shared__ __align__(16) f16 Ah[128][40], Al[128][40];
    __shared__ __align__(16) f16 Bh[128][40], Bl[128][40];
    const int tid = threadIdx.x, l = tid & 63, w = tid >> 6;
    const int wm = w >> 1, wn = w & 1;
    const int hi16 = l >> 4;
    const int m0 = blockIdx.y * 128, n0 = blockIdx.x * 128;

    f32x4 acc[4][4];
    #pragma unroll
    for (int mf = 0; mf < 4; ++mf)
        #pragma unroll
        for (int nf = 0; nf < 4; ++nf)
            acc[mf][nf] = (f32x4){0.f, 0.f, 0.f, 0.f};

    for (int k0 = 0; k0 < Kk; k0 += 32) {
        // A: 128 rows x 32 k (row-major, 16B-aligned rows: Kk=256)
        #pragma unroll
        for (int e = tid; e < 1024; e += 256) {
            const int row = e >> 3, q = e & 7;
            const int gr = m0 + row;
            float4 a4 = make_float4(0.f, 0.f, 0.f, 0.f);
            if (gr < Mm) a4 = *(const float4*)&A[(size_t)gr * Kk + k0 + 4 * q];
            const f16 h0 = (f16)a4.x, h1 = (f16)a4.y, h2 = (f16)a4.z, h3 = (f16)a4.w;
            Ah[row][4 * q + 0] = h0; Ah[row][4 * q + 1] = h1;
            Ah[row][4 * q + 2] = h2; Ah[row][4 * q + 3] = h3;
            Al[row][4 * q + 0] = (f16)(a4.x - (float)h0);
            Al[row][4 * q + 1] = (f16)(a4.y - (float)h1);
            Al[row][4 * q + 2] = (f16)(a4.z - (float)h2);
            Al[row][4 * q + 3] = (f16)(a4.w - (float)h3);
        }
        // B: 32 k-rows x 128 cols, transposed into [col][k] (float2: rows 8B-aligned)
        #pragma unroll
        for (int e = tid; e < 2048; e += 256) {
            const int kk = e >> 6, q = e & 63;
            const int gc = n0 + 2 * q;
            float2 b2 = make_float2(0.f, 0.f);
            const float* bp = &Bm[(size_t)(k0 + kk) * Nn + gc];
            if (gc + 1 < Nn)      b2 = *(const float2*)bp;
            else if (gc < Nn)     b2.x = bp[0];
            const f16 h0 = (f16)b2.x, h1 = (f16)b2.y;
            Bh[2 * q + 0][kk] = h0; Bh[2 * q + 1][kk] = h1;
            Bl[2 * q + 0][kk] = (f16)(b2.x - (float)h0);
            Bl[2 * q + 1][kk] = (f16)(b2.y - (float)h1);
        }
        __syncthreads();

        f16x8 ah_[4], al_[4], bh_[4], bl_[4];
        #pragma unroll
        for (int mf = 0; mf < 4; ++mf) {
            ah_[mf] = *(const f16x8*)&Ah[wm * 64 + mf * 16 + (l & 15)][hi16 * 8];
            al_[mf] = *(const f16x8*)&Al[wm * 64 + mf * 16 + (l & 15)][hi16 * 8];
        }
        #pragma unroll
        for (int nf = 0; nf < 4; ++nf) {
            bh_[nf] = *(const f16x8*)&Bh[wn * 64 + nf * 16 + (l & 15)][hi16 * 8];
            bl_[nf] = *(const f16x8*)&Bl[wn * 64 + nf * 16 + (l & 15)][hi16 * 8];
        }
        #pragma unroll
        for (int mf = 0; mf < 4; ++mf)
            #pragma unroll
            for (int nf = 0; nf < 4; ++nf) {
                acc[mf][nf] = __builtin_amdgcn_mfma_f32_16x16x32_f16(ah_[mf], bh_[nf], acc[mf][nf], 0, 0, 0);
                acc[mf][nf] = __builtin_amdgcn_mfma_f32_16x16x32_f16(ah_[mf], bl_[nf], acc[mf][nf], 0, 0, 0);
                acc[mf][nf] = __builtin_amdgcn_mfma_f32_16x16x32_f16(al_[mf], bh_[nf], acc[mf][nf], 0, 0, 0);
            }
        __syncthreads();
    }

    #pragma unroll
    for (int mf = 0; mf < 4; ++mf) {
        #pragma unroll
        for (int nf = 0; nf < 4; ++nf) {
            const int col = n0 + wn * 64 + nf * 16 + (l & 15);
            if (col >= Nn) continue;
            const float bv = bias[col];
            #pragma unroll
            for (int rr = 0; rr < 4; ++rr) {
                const int row = m0 + wm * 64 + mf * 16 + hi16 * 4 + rr;
                if (row < Mm)
                    C[(size_t)row * Nn + col] = acc[mf][nf][rr] + bv;
            }
        }
    }
}

// ---------------- chunk driver ----------------
template<int CC>
static void run_chunk(bool first, const float* X, int C_in, int c0,
                      const int* cols, const float* vals, const float* W,
                      uint4* const sl[3], float* part, hipStream_t stream)
{
    constexpr int LPR = CC / 8;
    constexpr int RPB = 256 / LPR;
    const int NB = (MR + RPB - 1) / RPB;

    tile_slab_kernel<CC><<<NB, 256, 0, stream>>>(X, C_in, c0, sl[0]);
    // k=1: spmm(0->1) + proj(slab 0)
    if (first)
        step_kernel<CC, false, true ><<<NB + PB, 256, 0, stream>>>(
            sl[0], sl[0], sl[1], cols, vals, W, part, C_in, c0, 0, NB);
    else
        step_kernel<CC, false, false><<<NB + PB, 256, 0, stream>>>(
            sl[0], sl[0], sl[1], cols, vals, W, part, C_in, c0, 0, NB);
    for (int k = 2; k < KC; ++k) {
        step_kernel<CC, true, false><<<NB + PB, 256, 0, stream>>>(
            sl[(k - 1) % 3], sl[(k - 2) % 3], sl[k % 3],
            cols, vals, W, part, C_in, c0, k - 1, NB);
    }
    proj_only_kernel<CC><<<PB, 256, 0, stream>>>(sl[(KC - 1) % 3], W, part, C_in, c0, KC - 1);
}

extern "C" void kernel_launch(void* const* d_in, const int* in_sizes, int n_in,
                              void* d_out, int out_size, void* d_ws, size_t ws_size,
                              hipStream_t stream)
{
    (void)in_sizes; (void)n_in; (void)out_size; (void)ws_size;
    const float* x     = (const float*)d_in[0];
    const int*   cols  = (const int*)  d_in[2];
    const float* vals  = (const float*)d_in[3];
    const float* W1    = (const float*)d_in[4];
    const float* Wc    = (const float*)d_in[5];
    const float* gamma = (const float*)d_in[7];
    const float* beta  = (const float*)d_in[8];
    const float* fc2w  = (const float*)d_in[9];
    const float* fc2b  = (const float*)d_in[10];
    const float* fc3w  = (const float*)d_in[11];
    const float* fc3b  = (const float*)d_in[12];

    const size_t MT   = (size_t)MR * 64;
    const size_t SLOT = (size_t)MR * 8;          // uint4 per slab slot (CC=64 sizing)
    uint4* slabs = (uint4*)d_ws;
    uint4* sl[3] = { slabs, slabs + SLOT, slabs + 2 * SLOT };
    float* part = (float*)(slabs + 3 * SLOT);    // [8][NN][64]
    float* acc  = part + MT;
    float* H    = acc + (size_t)NN * 64;
    float* f2   = H + (size_t)NN * 64;
    float* bnp  = f2 + (size_t)NN * 256;

    for (int li = 0; li < 6; ++li) {
        const int C_in = (li == 0) ? ND : 64;
        const float* X = (li == 0) ? x : H;
        const float* W = (li == 0) ? W1 : Wc + (size_t)(li - 1) * KC * (NA * 64) * 64;
        const int nfull = C_in / 64;
        for (int c = 0; c < nfull; ++c)
            run_chunk<64>(c == 0, X, C_in, c * 64, cols, vals, W, sl, part, stream);
        if (C_in % 64)
            run_chunk<32>(false, X, C_in, nfull * 64, cols, vals, W, sl, part, stream);

        bn_reduce_kernel<<<(NN * 64 + 255) / 256, 256, 0, stream>>>(part, acc);
        bn_stats_kernel<<<64, 256, 0, stream>>>(acc, gamma + li * 64, beta + li * 64, bnp);
        bn_apply_kernel<<<(NN * 64 + 255) / 256, 256, 0, stream>>>(acc, bnp, H);
    }

    gemm_bias_kernel<true><<<dim3(2, 54), 256, 0, stream>>>(H, fc2w, fc2b, f2, NN, 256, 64);
    fc3_mfma_kernel<<<dim3(54, 54), 256, 0, stream>>>(f2, fc3w, fc3b, (float*)d_out);
}